// Round 1
// baseline (1213.567 us; speedup 1.0000x reference)
//
#include <hip/hip_runtime.h>
#include <hip/hip_bf16.h>

// Problem constants
#define TSEQ 2048
#define DM   1024
#define NH   16
#define HDIM 64
#define NB   2
// flat size of one [B][H][T][HD] tensor = one [B][T][D] tensor
#define TEN4M 4194304

// ---------------------------------------------------------------------------
// Kernel 1: QKV projection.
// Computes q/k/v[b][h][t][e] = sum_d x[b,t,d] * W{q,k,v}[h,d,e]
// Grid: (4096/128, 3*16). Block 256. Tile: 128 rows (t) x 64 cols (e=HD).
// ---------------------------------------------------------------------------
__global__ __launch_bounds__(256) void qkv_kernel(
    const float* __restrict__ x,    // [4096][1024]  (B*T rows)
    const float* __restrict__ Wq,   // [16][1024][64]
    const float* __restrict__ Wk,
    const float* __restrict__ Wv,
    float* __restrict__ qkv)        // [3][B][H][T][HD]
{
    __shared__ float xs[16][129];   // [k][row], pad->stride 129 (odd: 2-way max)
    __shared__ float wsh[16][65];   // [k][col]

    const int tid = threadIdx.x;
    const int m0  = blockIdx.x * 128;
    const int mat = blockIdx.y >> 4;        // 0=q,1=k,2=v
    const int h   = blockIdx.y & 15;

    const float* W = (mat == 0 ? Wq : (mat == 1 ? Wk : Wv)) + (size_t)h * (DM * HDIM);

    const int tr = tid >> 4, tc = tid & 15;
    const int r0 = tr * 8, c0 = tc * 4;

    float acc[8][4];
#pragma unroll
    for (int i = 0; i < 8; ++i)
#pragma unroll
        for (int j = 0; j < 4; ++j) acc[i][j] = 0.f;

    for (int kc = 0; kc < DM / 16; ++kc) {
        // stage x tile: 128 rows x 16 d, transposed into xs[k][row]
#pragma unroll
        for (int it = 0; it < 2; ++it) {
            int li  = it * 256 + tid;
            int row = li >> 2, dq = li & 3;
            const float4 v = *reinterpret_cast<const float4*>(
                &x[(size_t)(m0 + row) * DM + kc * 16 + dq * 4]);
            xs[dq * 4 + 0][row] = v.x;
            xs[dq * 4 + 1][row] = v.y;
            xs[dq * 4 + 2][row] = v.z;
            xs[dq * 4 + 3][row] = v.w;
        }
        {
            int kk = tid >> 4, eq = tid & 15;
            const float4 v = *reinterpret_cast<const float4*>(
                &W[(size_t)(kc * 16 + kk) * HDIM + eq * 4]);
            wsh[kk][eq * 4 + 0] = v.x;
            wsh[kk][eq * 4 + 1] = v.y;
            wsh[kk][eq * 4 + 2] = v.z;
            wsh[kk][eq * 4 + 3] = v.w;
        }
        __syncthreads();
#pragma unroll
        for (int k = 0; k < 16; ++k) {
            float a[8], b[4];
#pragma unroll
            for (int i = 0; i < 8; ++i) a[i] = xs[k][r0 + i];
#pragma unroll
            for (int j = 0; j < 4; ++j) b[j] = wsh[k][c0 + j];
#pragma unroll
            for (int i = 0; i < 8; ++i)
#pragma unroll
                for (int j = 0; j < 4; ++j) acc[i][j] += a[i] * b[j];
        }
        __syncthreads();
    }

    float* out = qkv + (size_t)mat * TEN4M;
#pragma unroll
    for (int i = 0; i < 8; ++i) {
        int m = m0 + r0 + i;
        int b = m >> 11, t = m & (TSEQ - 1);
        float* o = out + ((size_t)(b * NH + h) * TSEQ + t) * HDIM;
#pragma unroll
        for (int j = 0; j < 4; ++j) o[c0 + j] = acc[i][j];
    }
}

// ---------------------------------------------------------------------------
// Kernel 2: causal flash attention per (b,h). Q-tile 64 rows, KV-tiles of 64.
// Grid: (T/64, B*H). Block 256 (16x16 threads, each 4 rows x 4 cols).
// ---------------------------------------------------------------------------
__global__ __launch_bounds__(256) void attn_kernel(
    const float* __restrict__ qkv,   // [3][B*H][T][HD]
    float* __restrict__ concat)      // [B][T][H*HD]
{
    __shared__ float Qs[64][65];
    __shared__ float Ks[64][65];     // reused as P after scores
    __shared__ float Vs[64][65];

    const int tid = threadIdx.x;
    const int qt  = blockIdx.x;
    const int bh  = blockIdx.y;
    const int b   = bh >> 4, h = bh & 15;

    const float* Q = qkv + (size_t)bh * TSEQ * HDIM;
    const float* K = Q + (size_t)TEN4M;
    const float* V = K + (size_t)TEN4M;

    // stage Q tile once
#pragma unroll
    for (int it = 0; it < 4; ++it) {
        int li = it * 256 + tid;
        int row = li >> 4, eq = li & 15;
        const float4 v = *reinterpret_cast<const float4*>(
            &Q[(size_t)(qt * 64 + row) * HDIM + eq * 4]);
        Qs[row][eq * 4 + 0] = v.x;
        Qs[row][eq * 4 + 1] = v.y;
        Qs[row][eq * 4 + 2] = v.z;
        Qs[row][eq * 4 + 3] = v.w;
    }

    const int tr = tid >> 4, tc = tid & 15;
    const int r0 = tr * 4, c0 = tc * 4;

    float m[4], l[4], acc[4][4];
#pragma unroll
    for (int i = 0; i < 4; ++i) {
        m[i] = -1e30f;
        l[i] = 0.f;
#pragma unroll
        for (int j = 0; j < 4; ++j) acc[i][j] = 0.f;
    }

    for (int jt = 0; jt <= qt; ++jt) {
        __syncthreads();  // prior PV reads of Ks/Vs done before restage
#pragma unroll
        for (int it = 0; it < 4; ++it) {
            int li = it * 256 + tid;
            int row = li >> 4, eq = li & 15;
            const float4 kv = *reinterpret_cast<const float4*>(
                &K[(size_t)(jt * 64 + row) * HDIM + eq * 4]);
            Ks[row][eq * 4 + 0] = kv.x;
            Ks[row][eq * 4 + 1] = kv.y;
            Ks[row][eq * 4 + 2] = kv.z;
            Ks[row][eq * 4 + 3] = kv.w;
            const float4 vv = *reinterpret_cast<const float4*>(
                &V[(size_t)(jt * 64 + row) * HDIM + eq * 4]);
            Vs[row][eq * 4 + 0] = vv.x;
            Vs[row][eq * 4 + 1] = vv.y;
            Vs[row][eq * 4 + 2] = vv.z;
            Vs[row][eq * 4 + 3] = vv.w;
        }
        __syncthreads();

        // scores s = Q K^T
        float s[4][4];
#pragma unroll
        for (int i = 0; i < 4; ++i)
#pragma unroll
            for (int j = 0; j < 4; ++j) s[i][j] = 0.f;
#pragma unroll 4
        for (int e = 0; e < HDIM; ++e) {
            float a[4], bb[4];
#pragma unroll
            for (int i = 0; i < 4; ++i) a[i] = Qs[r0 + i][e];
#pragma unroll
            for (int j = 0; j < 4; ++j) bb[j] = Ks[c0 + j][e];
#pragma unroll
            for (int i = 0; i < 4; ++i)
#pragma unroll
                for (int j = 0; j < 4; ++j) s[i][j] += a[i] * bb[j];
        }
        const float scale = 0.125f;  // HD^-0.5
        if (jt == qt) {
#pragma unroll
            for (int i = 0; i < 4; ++i)
#pragma unroll
                for (int j = 0; j < 4; ++j)
                    s[i][j] = (c0 + j <= r0 + i) ? s[i][j] * scale : -1e30f;
        } else {
#pragma unroll
            for (int i = 0; i < 4; ++i)
#pragma unroll
                for (int j = 0; j < 4; ++j) s[i][j] *= scale;
        }

        // online softmax (row groups = 16 lanes sharing tr)
#pragma unroll
        for (int i = 0; i < 4; ++i) {
            float tm = fmaxf(fmaxf(s[i][0], s[i][1]), fmaxf(s[i][2], s[i][3]));
#pragma unroll
            for (int off = 1; off < 16; off <<= 1)
                tm = fmaxf(tm, __shfl_xor(tm, off, 64));
            float mnew = fmaxf(m[i], tm);
            float corr = expf(m[i] - mnew);
            float ps = 0.f;
#pragma unroll
            for (int j = 0; j < 4; ++j) {
                s[i][j] = expf(s[i][j] - mnew);
                ps += s[i][j];
            }
#pragma unroll
            for (int off = 1; off < 16; off <<= 1)
                ps += __shfl_xor(ps, off, 64);
            l[i] = l[i] * corr + ps;
            m[i] = mnew;
#pragma unroll
            for (int j = 0; j < 4; ++j) acc[i][j] *= corr;
        }
        __syncthreads();  // all score reads of Ks done
        // write P into Ks buffer
#pragma unroll
        for (int i = 0; i < 4; ++i)
#pragma unroll
            for (int j = 0; j < 4; ++j) Ks[r0 + i][c0 + j] = s[i][j];
        __syncthreads();

        // PV: acc[i][j] += sum_c P[r][c] * V[c][e]
#pragma unroll 4
        for (int c = 0; c < 64; ++c) {
            float pr[4], vv[4];
#pragma unroll
            for (int i = 0; i < 4; ++i) pr[i] = Ks[r0 + i][c];
#pragma unroll
            for (int j = 0; j < 4; ++j) vv[j] = Vs[c][c0 + j];
#pragma unroll
            for (int i = 0; i < 4; ++i)
#pragma unroll
                for (int j = 0; j < 4; ++j) acc[i][j] += pr[i] * vv[j];
        }
    }

    // epilogue: normalize and write concat[b][t][h*64+e]
#pragma unroll
    for (int i = 0; i < 4; ++i) {
        float inv = 1.0f / l[i];
        int t = qt * 64 + r0 + i;
        float* o = concat + ((size_t)(b * TSEQ + t)) * DM + h * HDIM;
#pragma unroll
        for (int j = 0; j < 4; ++j) o[c0 + j] = acc[i][j] * inv;
    }
}

// ---------------------------------------------------------------------------
// Kernel 3: output projection out = concat @ Wp^T + bp
// Grid: (4096/128, 1024/64). Block 256. Tile 128 x 64, 8x4 per thread.
// ---------------------------------------------------------------------------
__global__ __launch_bounds__(256) void proj_kernel(
    const float* __restrict__ concat,  // [4096][1024]
    const float* __restrict__ Wp,      // [1024][1024] (out = c @ Wp^T)
    const float* __restrict__ bp,      // [1024]
    float* __restrict__ out)           // [4096][1024]
{
    __shared__ float cs[16][129];   // [k][row]
    __shared__ float ps[16][65];    // [k][dcol]

    const int tid = threadIdx.x;
    const int m0 = blockIdx.x * 128;
    const int n0 = blockIdx.y * 64;

    const int tr = tid >> 4, tc = tid & 15;
    const int r0 = tr * 8, c0 = tc * 4;

    float acc[8][4];
#pragma unroll
    for (int i = 0; i < 8; ++i)
#pragma unroll
        for (int j = 0; j < 4; ++j) acc[i][j] = 0.f;

    for (int kc = 0; kc < DM / 16; ++kc) {
#pragma unroll
        for (int it = 0; it < 2; ++it) {
            int li = it * 256 + tid;
            int row = li >> 2, dq = li & 3;
            const float4 v = *reinterpret_cast<const float4*>(
                &concat[(size_t)(m0 + row) * DM + kc * 16 + dq * 4]);
            cs[dq * 4 + 0][row] = v.x;
            cs[dq * 4 + 1][row] = v.y;
            cs[dq * 4 + 2][row] = v.z;
            cs[dq * 4 + 3][row] = v.w;
        }
        {
            int dcol = tid >> 2, jq = tid & 3;
            const float4 v = *reinterpret_cast<const float4*>(
                &Wp[(size_t)(n0 + dcol) * DM + kc * 16 + jq * 4]);
            ps[jq * 4 + 0][dcol] = v.x;
            ps[jq * 4 + 1][dcol] = v.y;
            ps[jq * 4 + 2][dcol] = v.z;
            ps[jq * 4 + 3][dcol] = v.w;
        }
        __syncthreads();
#pragma unroll
        for (int k = 0; k < 16; ++k) {
            float a[8], b[4];
#pragma unroll
            for (int i = 0; i < 8; ++i) a[i] = cs[k][r0 + i];
#pragma unroll
            for (int j = 0; j < 4; ++j) b[j] = ps[k][c0 + j];
#pragma unroll
            for (int i = 0; i < 8; ++i)
#pragma unroll
                for (int j = 0; j < 4; ++j) acc[i][j] += a[i] * b[j];
        }
        __syncthreads();
    }

    float bb[4];
#pragma unroll
    for (int j = 0; j < 4; ++j) bb[j] = bp[n0 + c0 + j];
#pragma unroll
    for (int i = 0; i < 8; ++i) {
#pragma unroll
        for (int j = 0; j < 4; ++j)
            out[(size_t)(m0 + r0 + i) * DM + n0 + c0 + j] = acc[i][j] + bb[j];
    }
}

// ---------------------------------------------------------------------------
extern "C" void kernel_launch(void* const* d_in, const int* in_sizes, int n_in,
                              void* d_out, int out_size, void* d_ws, size_t ws_size,
                              hipStream_t stream) {
    const float* x  = (const float*)d_in[0];
    const float* Wq = (const float*)d_in[1];
    const float* Wk = (const float*)d_in[2];
    const float* Wv = (const float*)d_in[3];
    const float* Wp = (const float*)d_in[4];
    const float* bp = (const float*)d_in[5];
    float* out = (float*)d_out;

    float* ws     = (float*)d_ws;
    float* qkv    = ws;                      // [3][B*H][T][HD] = 3 * 4M floats
    float* concat = ws + (size_t)3 * TEN4M;  // [B][T][D]       = 4M floats

    dim3 blk(256);
    qkv_kernel<<<dim3(4096 / 128, 3 * NH), blk, 0, stream>>>(x, Wq, Wk, Wv, qkv);
    attn_kernel<<<dim3(TSEQ / 64, NB * NH), blk, 0, stream>>>(qkv, concat);
    proj_kernel<<<dim3(4096 / 128, DM / 64), blk, 0, stream>>>(concat, Wp, bp, out);
}

// Round 2
// 165.143 us; speedup vs baseline: 7.3486x; 7.3486x over previous
//
#include <hip/hip_runtime.h>
#include <hip/hip_bf16.h>

#define TSEQ 2048
#define DM   1024
#define NH   16
#define HDIM 64
#define NB   2
#define BT   (NB*TSEQ)   // 4096
// Q pre-scale: HD^-0.5 * log2(e) so softmax uses exp2
#define QSCALE 0.1803368801111204f

typedef __attribute__((ext_vector_type(8))) short bf16x8;
typedef __attribute__((ext_vector_type(4))) float f32x4;

union BF8 { bf16x8 v; ushort u[8]; };

static __device__ __forceinline__ ushort f2b(float x) {
    unsigned u = __float_as_uint(x);
    return (ushort)((u + 0x7fff + ((u >> 16) & 1)) >> 16);  // RNE, finite inputs
}

// ---------------------------------------------------------------------------
// Prep A: f32 -> bf16 bulk convert (8 elems/thread)
// ---------------------------------------------------------------------------
__global__ __launch_bounds__(256) void cvt_kernel(const float* __restrict__ src,
                                                  ushort* __restrict__ dst, int n8) {
    int i = blockIdx.x * 256 + threadIdx.x;
    if (i >= n8) return;
    const float4* s = reinterpret_cast<const float4*>(src);
    float4 a = s[2*i], b = s[2*i+1];
    union { ushort u[8]; int4 v; } r;
    r.u[0]=f2b(a.x); r.u[1]=f2b(a.y); r.u[2]=f2b(a.z); r.u[3]=f2b(a.w);
    r.u[4]=f2b(b.x); r.u[5]=f2b(b.y); r.u[6]=f2b(b.z); r.u[7]=f2b(b.w);
    reinterpret_cast<int4*>(dst)[i] = r.v;
}

// ---------------------------------------------------------------------------
// Prep B: transpose Wq/Wk/Wv per head: f32 [D][HD] -> bf16 [HD][D]
// grid (D/64, 3*16), block 256
// ---------------------------------------------------------------------------
__global__ __launch_bounds__(256) void wt_kernel(const float* __restrict__ Wq,
                                                 const float* __restrict__ Wk,
                                                 const float* __restrict__ Wv,
                                                 ushort* __restrict__ wtb) {
    __shared__ float tile[64][65];
    const int t = threadIdx.x;
    const int k0 = blockIdx.x * 64;
    const int mat = blockIdx.y >> 4, h = blockIdx.y & 15;
    const float* W = (mat == 0 ? Wq : (mat == 1 ? Wk : Wv)) + (size_t)h * DM * HDIM;
#pragma unroll
    for (int it = 0; it < 4; ++it) {
        int row = it*16 + (t>>4), c4 = (t&15)*4;
        float4 v = *reinterpret_cast<const float4*>(&W[(size_t)(k0+row)*HDIM + c4]);
        tile[row][c4+0]=v.x; tile[row][c4+1]=v.y; tile[row][c4+2]=v.z; tile[row][c4+3]=v.w;
    }
    __syncthreads();
    ushort* out = wtb + (size_t)(mat*NH + h) * (HDIM*DM);
#pragma unroll
    for (int it = 0; it < 4; ++it) {
        int n = it*16 + (t>>4), kc = (t&15)*4;
        union { ushort u[4]; uint2 v; } r;
#pragma unroll
        for (int j = 0; j < 4; ++j) r.u[j] = f2b(tile[kc+j][n]);
        *reinterpret_cast<uint2*>(&out[(size_t)n*DM + k0 + kc]) = r.v;
    }
}

// ---------------------------------------------------------------------------
// QKV GEMM: q/k/v[bh][t][e] = x[t][:] @ W[h][:][e], bf16 MFMA.
// grid (BT/128, 3*16), block 256 (4 waves). Tile 128x64, BK=64.
// A-tile rows padded to 72 bf16 (144B: stride/16 odd -> optimal b128 banking).
// q is pre-scaled by QSCALE.
// ---------------------------------------------------------------------------
__global__ __launch_bounds__(256) void qkv_mfma(const ushort* __restrict__ xb,
                                                const ushort* __restrict__ wtb,
                                                ushort* __restrict__ qkvb) {
    __shared__ ushort As[128][72];
    __shared__ ushort Bs[64][72];
    const int tid = threadIdx.x;
    const int w = tid >> 6, l = tid & 63;
    const int lr = l & 15, lg = l >> 4;
    const int m0 = blockIdx.x * 128;
    const int mat = blockIdx.y >> 4, h = blockIdx.y & 15;
    const ushort* Wt = wtb + (size_t)(mat*NH + h) * (HDIM*DM);

    f32x4 acc[2][4];
#pragma unroll
    for (int a = 0; a < 2; ++a)
#pragma unroll
        for (int b = 0; b < 4; ++b) acc[a][b] = {0.f, 0.f, 0.f, 0.f};

    for (int kc = 0; kc < DM/64; ++kc) {
        __syncthreads();
#pragma unroll
        for (int it = 0; it < 4; ++it) {
            int u = it*256 + tid;
            int row = u >> 3, c16 = u & 7;
            *reinterpret_cast<bf16x8*>(&As[row][c16*8]) =
                *reinterpret_cast<const bf16x8*>(&xb[(size_t)(m0+row)*DM + kc*64 + c16*8]);
        }
#pragma unroll
        for (int it = 0; it < 2; ++it) {
            int u = it*256 + tid;
            int row = u >> 3, c16 = u & 7;
            *reinterpret_cast<bf16x8*>(&Bs[row][c16*8]) =
                *reinterpret_cast<const bf16x8*>(&Wt[(size_t)row*DM + kc*64 + c16*8]);
        }
        __syncthreads();
        bf16x8 af[2][2], bfr[4][2];
#pragma unroll
        for (int mf = 0; mf < 2; ++mf)
#pragma unroll
            for (int kk = 0; kk < 2; ++kk)
                af[mf][kk] = *reinterpret_cast<const bf16x8*>(&As[w*32 + mf*16 + lr][kk*32 + lg*8]);
#pragma unroll
        for (int nf = 0; nf < 4; ++nf)
#pragma unroll
            for (int kk = 0; kk < 2; ++kk)
                bfr[nf][kk] = *reinterpret_cast<const bf16x8*>(&Bs[nf*16 + lr][kk*32 + lg*8]);
#pragma unroll
        for (int mf = 0; mf < 2; ++mf)
#pragma unroll
            for (int nf = 0; nf < 4; ++nf)
#pragma unroll
                for (int kk = 0; kk < 2; ++kk)
                    acc[mf][nf] = __builtin_amdgcn_mfma_f32_16x16x32_bf16(
                        af[mf][kk], bfr[nf][kk], acc[mf][nf], 0, 0, 0);
    }
    const float qs = (mat == 0) ? QSCALE : 1.0f;
#pragma unroll
    for (int mf = 0; mf < 2; ++mf) {
#pragma unroll
        for (int i = 0; i < 4; ++i) {
            int m = m0 + w*32 + mf*16 + lg*4 + i;       // C/D: row=(l>>4)*4+i
            int b = m >> 11, tt = m & (TSEQ-1);
            ushort* o = qkvb + ((size_t)(mat*2*NH) + (size_t)(b*NH + h)) * (TSEQ*HDIM)
                        + (size_t)tt*HDIM;
#pragma unroll
            for (int nf = 0; nf < 4; ++nf)
                o[nf*16 + lr] = f2b(acc[mf][nf][i] * qs);   // col=l&15
        }
    }
}

// ---------------------------------------------------------------------------
// Causal flash attention, bf16 MFMA. grid (TSEQ/128, B*H), block 512 (8 waves).
// Wave w owns 16 q-rows (Q frags hoisted from global). KV tiles of 64.
// S^T not needed: P goes through per-wave LDS (no barrier).
// qt paired (x, 15-x) across the two bh halves -> balanced 2 blocks/CU.
// ---------------------------------------------------------------------------
__global__ __launch_bounds__(512) void attn_mfma(const ushort* __restrict__ qkvb,
                                                 ushort* __restrict__ concatb) {
    __shared__ ushort Ks[64][72];
    __shared__ ushort Vt[64][72];      // [e][s]
    __shared__ ushort Ps[8][16][72];   // per-wave P
    const int tid = threadIdx.x;
    const int w = tid >> 6, l = tid & 63;
    const int lr = l & 15, lg = l >> 4;
    const int bh = blockIdx.y;
    const int qt = (bh >= NH) ? (15 - (int)blockIdx.x) : (int)blockIdx.x;
    const int q0 = qt * 128, qw0 = q0 + w * 16;

    const ushort* Q = qkvb + (size_t)bh * (TSEQ*HDIM);
    const ushort* K = Q + (size_t)2*NH*TSEQ*HDIM;
    const ushort* V = K + (size_t)2*NH*TSEQ*HDIM;

    bf16x8 qf[2];
#pragma unroll
    for (int kk = 0; kk < 2; ++kk)
        qf[kk] = *reinterpret_cast<const bf16x8*>(&Q[(size_t)(qw0 + lr)*HDIM + kk*32 + lg*8]);

    f32x4 acc[4];
    float mrow[4], lrow[4];
#pragma unroll
    for (int i = 0; i < 4; ++i) { acc[i] = {0.f,0.f,0.f,0.f}; mrow[i] = -1e30f; lrow[i] = 0.f; }

    const int ntiles = 2*qt + 2;
    for (int jt = 0; jt < ntiles; ++jt) {
        const int s0 = jt * 64;
        __syncthreads();
        {
            // stage K: 512 threads x one 16B chunk
            int row = tid >> 3, c16 = tid & 7;
            *reinterpret_cast<bf16x8*>(&Ks[row][c16*8]) =
                *reinterpret_cast<const bf16x8*>(&K[(size_t)(s0+row)*HDIM + c16*8]);
            // stage V transposed: lane l -> s=l, e-chunk=w (conflict-free writes)
            BF8 vv; vv.v = *reinterpret_cast<const bf16x8*>(&V[(size_t)(s0+l)*HDIM + w*8]);
#pragma unroll
            for (int j = 0; j < 8; ++j) Vt[w*8 + j][l] = vv.u[j];
        }
        __syncthreads();
        if (s0 <= qw0 + 15) {           // wave has >=1 unmasked row
            f32x4 sf[4];
#pragma unroll
            for (int nf = 0; nf < 4; ++nf) sf[nf] = {0.f,0.f,0.f,0.f};
#pragma unroll
            for (int nf = 0; nf < 4; ++nf)
#pragma unroll
                for (int kk = 0; kk < 2; ++kk) {
                    bf16x8 kf = *reinterpret_cast<const bf16x8*>(&Ks[nf*16 + lr][kk*32 + lg*8]);
                    sf[nf] = __builtin_amdgcn_mfma_f32_16x16x32_bf16(qf[kk], kf, sf[nf], 0, 0, 0);
                }
            if (s0 + 63 > qw0) {        // diagonal tile: causal mask
#pragma unroll
                for (int nf = 0; nf < 4; ++nf) {
                    int scol = s0 + nf*16 + lr;
#pragma unroll
                    for (int i = 0; i < 4; ++i) {
                        int qrow = qw0 + lg*4 + i;
                        if (scol > qrow) sf[nf][i] = -1e30f;
                    }
                }
            }
            // online softmax (rows live on the 16 lanes sharing lg)
            float tm[4], corr[4], ps[4];
#pragma unroll
            for (int i = 0; i < 4; ++i)
                tm[i] = fmaxf(fmaxf(sf[0][i], sf[1][i]), fmaxf(sf[2][i], sf[3][i]));
#pragma unroll
            for (int off = 1; off < 16; off <<= 1)
#pragma unroll
                for (int i = 0; i < 4; ++i)
                    tm[i] = fmaxf(tm[i], __shfl_xor(tm[i], off, 64));
#pragma unroll
            for (int i = 0; i < 4; ++i) {
                float mnew = fmaxf(mrow[i], tm[i]);
                corr[i] = exp2f(mrow[i] - mnew);
                mrow[i] = mnew;
            }
#pragma unroll
            for (int nf = 0; nf < 4; ++nf)
#pragma unroll
                for (int i = 0; i < 4; ++i)
                    sf[nf][i] = exp2f(sf[nf][i] - mrow[i]);
#pragma unroll
            for (int i = 0; i < 4; ++i)
                ps[i] = (sf[0][i] + sf[1][i]) + (sf[2][i] + sf[3][i]);
#pragma unroll
            for (int off = 1; off < 16; off <<= 1)
#pragma unroll
                for (int i = 0; i < 4; ++i)
                    ps[i] += __shfl_xor(ps[i], off, 64);
#pragma unroll
            for (int i = 0; i < 4; ++i) lrow[i] = lrow[i]*corr[i] + ps[i];
#pragma unroll
            for (int nf = 0; nf < 4; ++nf)
#pragma unroll
                for (int i = 0; i < 4; ++i) acc[nf][i] *= corr[i];
            // P -> LDS (C-layout write), re-read as A-frags (same wave: no barrier)
#pragma unroll
            for (int nf = 0; nf < 4; ++nf)
#pragma unroll
                for (int i = 0; i < 4; ++i)
                    Ps[w][lg*4 + i][nf*16 + lr] = f2b(sf[nf][i]);
#pragma unroll
            for (int kk = 0; kk < 2; ++kk) {
                bf16x8 pf = *reinterpret_cast<const bf16x8*>(&Ps[w][lr][kk*32 + lg*8]);
#pragma unroll
                for (int nf = 0; nf < 4; ++nf) {
                    bf16x8 vf = *reinterpret_cast<const bf16x8*>(&Vt[nf*16 + lr][kk*32 + lg*8]);
                    acc[nf] = __builtin_amdgcn_mfma_f32_16x16x32_bf16(pf, vf, acc[nf], 0, 0, 0);
                }
            }
        }
    }
    const int b = bh >> 4, h = bh & 15;
#pragma unroll
    for (int i = 0; i < 4; ++i) {
        float inv = 1.0f / lrow[i];
        int t = qw0 + lg*4 + i;
        ushort* o = concatb + ((size_t)(b*TSEQ + t))*DM + h*HDIM;
#pragma unroll
        for (int nf = 0; nf < 4; ++nf)
            o[nf*16 + lr] = f2b(acc[nf][i] * inv);
    }
}

// ---------------------------------------------------------------------------
// Output projection: out[m][n] = concat[m][:] @ Wp[n][:] + bp[n], fp32 out.
// grid (BT/128, DM/64), block 256. Wp rows give contiguous B-frags directly.
// ---------------------------------------------------------------------------
__global__ __launch_bounds__(256) void proj_mfma(const ushort* __restrict__ cb,
                                                 const ushort* __restrict__ wpb,
                                                 const float* __restrict__ bp,
                                                 float* __restrict__ out) {
    __shared__ ushort As[128][72];
    __shared__ ushort Bs[64][72];
    const int tid = threadIdx.x;
    const int w = tid >> 6, l = tid & 63;
    const int lr = l & 15, lg = l >> 4;
    const int m0 = blockIdx.x * 128;
    const int n0 = blockIdx.y * 64;

    f32x4 acc[2][4];
#pragma unroll
    for (int a = 0; a < 2; ++a)
#pragma unroll
        for (int b = 0; b < 4; ++b) acc[a][b] = {0.f, 0.f, 0.f, 0.f};

    for (int kc = 0; kc < DM/64; ++kc) {
        __syncthreads();
#pragma unroll
        for (int it = 0; it < 4; ++it) {
            int u = it*256 + tid;
            int row = u >> 3, c16 = u & 7;
            *reinterpret_cast<bf16x8*>(&As[row][c16*8]) =
                *reinterpret_cast<const bf16x8*>(&cb[(size_t)(m0+row)*DM + kc*64 + c16*8]);
        }
#pragma unroll
        for (int it = 0; it < 2; ++it) {
            int u = it*256 + tid;
            int row = u >> 3, c16 = u & 7;
            *reinterpret_cast<bf16x8*>(&Bs[row][c16*8]) =
                *reinterpret_cast<const bf16x8*>(&wpb[(size_t)(n0+row)*DM + kc*64 + c16*8]);
        }
        __syncthreads();
        bf16x8 af[2][2], bfr[4][2];
#pragma unroll
        for (int mf = 0; mf < 2; ++mf)
#pragma unroll
            for (int kk = 0; kk < 2; ++kk)
                af[mf][kk] = *reinterpret_cast<const bf16x8*>(&As[w*32 + mf*16 + lr][kk*32 + lg*8]);
#pragma unroll
        for (int nf = 0; nf < 4; ++nf)
#pragma unroll
            for (int kk = 0; kk < 2; ++kk)
                bfr[nf][kk] = *reinterpret_cast<const bf16x8*>(&Bs[nf*16 + lr][kk*32 + lg*8]);
#pragma unroll
        for (int mf = 0; mf < 2; ++mf)
#pragma unroll
            for (int nf = 0; nf < 4; ++nf)
#pragma unroll
                for (int kk = 0; kk < 2; ++kk)
                    acc[mf][nf] = __builtin_amdgcn_mfma_f32_16x16x32_bf16(
                        af[mf][kk], bfr[nf][kk], acc[mf][nf], 0, 0, 0);
    }
#pragma unroll
    for (int mf = 0; mf < 2; ++mf) {
#pragma unroll
        for (int i = 0; i < 4; ++i) {
            int m = m0 + w*32 + mf*16 + lg*4 + i;
#pragma unroll
            for (int nf = 0; nf < 4; ++nf) {
                int n = n0 + nf*16 + lr;
                out[(size_t)m*DM + n] = acc[mf][nf][i] + bp[n];
            }
        }
    }
}

// ---------------------------------------------------------------------------
extern "C" void kernel_launch(void* const* d_in, const int* in_sizes, int n_in,
                              void* d_out, int out_size, void* d_ws, size_t ws_size,
                              hipStream_t stream) {
    const float* x  = (const float*)d_in[0];
    const float* Wq = (const float*)d_in[1];
    const float* Wk = (const float*)d_in[2];
    const float* Wv = (const float*)d_in[3];
    const float* Wp = (const float*)d_in[4];
    const float* bp = (const float*)d_in[5];
    float* out = (float*)d_out;

    ushort* ws   = (ushort*)d_ws;
    ushort* xb   = ws;                                    // BT*DM
    ushort* wtb  = xb  + (size_t)BT*DM;                   // 3*NH*HDIM*DM
    ushort* wpb  = wtb + (size_t)3*NH*HDIM*DM;            // DM*DM
    ushort* qkvb = wpb + (size_t)DM*DM;                   // 3*2*NH*TSEQ*HDIM
    ushort* cb   = qkvb + (size_t)3*2*NH*TSEQ*HDIM;       // BT*DM

    cvt_kernel<<<dim3((BT*DM/8 + 255)/256), 256, 0, stream>>>(x, xb, BT*DM/8);
    wt_kernel<<<dim3(DM/64, 3*NH), 256, 0, stream>>>(Wq, Wk, Wv, wtb);
    cvt_kernel<<<dim3(DM*DM/8/256), 256, 0, stream>>>(Wp, wpb, DM*DM/8);
    qkv_mfma<<<dim3(BT/128, 3*NH), 256, 0, stream>>>(xb, wtb, qkvb);
    attn_mfma<<<dim3(TSEQ/128, NB*NH), 512, 0, stream>>>(qkvb, cb);
    proj_mfma<<<dim3(BT/128, DM/64), 256, 0, stream>>>(cb, wpb, bp, out);
}

// Round 3
// 163.084 us; speedup vs baseline: 7.4414x; 1.0126x over previous
//
#include <hip/hip_runtime.h>
#include <hip/hip_bf16.h>

#define TSEQ 2048
#define DM   1024
#define NH   16
#define HDIM 64
#define NB   2
#define BT   (NB*TSEQ)   // 4096
// Q pre-scale: HD^-0.5 * log2(e) so softmax runs in exp2 domain
#define QSCALE 0.1803368801111204f

typedef __attribute__((ext_vector_type(8))) short bf16x8;
typedef __attribute__((ext_vector_type(4))) float f32x4;

union BF8 { bf16x8 v; ushort u[8]; };

static __device__ __forceinline__ ushort f2b(float x) {
    unsigned u = __float_as_uint(x);
    return (ushort)((u + 0x7fff + ((u >> 16) & 1)) >> 16);  // RNE, finite inputs
}

static __device__ __forceinline__ void gload16(const void* g, void* l) {
    __builtin_amdgcn_global_load_lds((const __attribute__((address_space(1))) void*)g,
                                     (__attribute__((address_space(3))) void*)l, 16, 0, 0);
}

// ---------------------------------------------------------------------------
// Prep A: f32 -> bf16 bulk convert (8 elems/thread)
// ---------------------------------------------------------------------------
__global__ __launch_bounds__(256) void cvt_kernel(const float* __restrict__ src,
                                                  ushort* __restrict__ dst, int n8) {
    int i = blockIdx.x * 256 + threadIdx.x;
    if (i >= n8) return;
    const float4* s = reinterpret_cast<const float4*>(src);
    float4 a = s[2*i], b = s[2*i+1];
    union { ushort u[8]; int4 v; } r;
    r.u[0]=f2b(a.x); r.u[1]=f2b(a.y); r.u[2]=f2b(a.z); r.u[3]=f2b(a.w);
    r.u[4]=f2b(b.x); r.u[5]=f2b(b.y); r.u[6]=f2b(b.z); r.u[7]=f2b(b.w);
    reinterpret_cast<int4*>(dst)[i] = r.v;
}

// ---------------------------------------------------------------------------
// Prep B: transpose Wq/Wk/Wv per head: f32 [D][HD] -> bf16 rows [mat][h][e][D]
// grid (D/64, 3*16), block 256
// ---------------------------------------------------------------------------
__global__ __launch_bounds__(256) void wt_kernel(const float* __restrict__ Wq,
                                                 const float* __restrict__ Wk,
                                                 const float* __restrict__ Wv,
                                                 ushort* __restrict__ wtb) {
    __shared__ float tile[64][65];
    const int t = threadIdx.x;
    const int k0 = blockIdx.x * 64;
    const int mat = blockIdx.y >> 4, h = blockIdx.y & 15;
    const float* W = (mat == 0 ? Wq : (mat == 1 ? Wk : Wv)) + (size_t)h * DM * HDIM;
#pragma unroll
    for (int it = 0; it < 4; ++it) {
        int row = it*16 + (t>>4), c4 = (t&15)*4;
        float4 v = *reinterpret_cast<const float4*>(&W[(size_t)(k0+row)*HDIM + c4]);
        tile[row][c4+0]=v.x; tile[row][c4+1]=v.y; tile[row][c4+2]=v.z; tile[row][c4+3]=v.w;
    }
    __syncthreads();
    ushort* out = wtb + (size_t)(mat*NH + h) * (HDIM*DM);
#pragma unroll
    for (int it = 0; it < 4; ++it) {
        int n = it*16 + (t>>4), kc = (t&15)*4;
        union { ushort u[4]; uint2 v; } r;
#pragma unroll
        for (int j = 0; j < 4; ++j) r.u[j] = f2b(tile[kc+j][n]);
        *reinterpret_cast<uint2*>(&out[(size_t)n*DM + k0 + kc]) = r.v;
    }
}

// ---------------------------------------------------------------------------
// m97-style GEMM: C[M][N] = A[M][1024] @ B[N][1024]^T
// 128x128 tile, BK=64, 4 waves (2x2), global_load_lds width 16, linear LDS.
// EPI 0: qkv scatter (bf16, QSCALE on mat 0). EPI 1: proj (f32 + bias).
// ---------------------------------------------------------------------------
template<int EPI>
__global__ __launch_bounds__(256) void gemm_bt(const ushort* __restrict__ A,
                                               const ushort* __restrict__ B,
                                               const float* __restrict__ bias,
                                               void* __restrict__ C) {
    __shared__ ushort As[128*64];
    __shared__ ushort Bs[128*64];
    const int tid = threadIdx.x;
    const int w = tid >> 6, l = tid & 63;
    const int lr = l & 15, lg = l >> 4;
    const int wr = (w >> 1) * 64, wc = (w & 1) * 64;
    const int m0 = blockIdx.x * 128, n0 = blockIdx.y * 128;
    const int srow = l >> 3;            // staging row within 8-row chunk
    const int scol = (l & 7) * 8;       // staging col (ushorts)

    f32x4 acc[4][4];
#pragma unroll
    for (int a = 0; a < 4; ++a)
#pragma unroll
        for (int b = 0; b < 4; ++b) acc[a][b] = {0.f, 0.f, 0.f, 0.f};

    for (int kc = 0; kc < DM/64; ++kc) {
        __syncthreads();
#pragma unroll
        for (int c = 0; c < 4; ++c) {
            int chunk = w*4 + c;
            int r = chunk*8 + srow;
            gload16(&A[(size_t)(m0+r)*DM + kc*64 + scol], &As[chunk*512]);
            gload16(&B[(size_t)(n0+r)*DM + kc*64 + scol], &Bs[chunk*512]);
        }
        __syncthreads();
#pragma unroll
        for (int kk = 0; kk < 2; ++kk) {
            bf16x8 af[4], bf[4];
#pragma unroll
            for (int mf = 0; mf < 4; ++mf)
                af[mf] = *reinterpret_cast<const bf16x8*>(&As[(wr + mf*16 + lr)*64 + kk*32 + lg*8]);
#pragma unroll
            for (int nf = 0; nf < 4; ++nf)
                bf[nf] = *reinterpret_cast<const bf16x8*>(&Bs[(wc + nf*16 + lr)*64 + kk*32 + lg*8]);
            __builtin_amdgcn_s_setprio(1);
#pragma unroll
            for (int mf = 0; mf < 4; ++mf)
#pragma unroll
                for (int nf = 0; nf < 4; ++nf)
                    acc[mf][nf] = __builtin_amdgcn_mfma_f32_16x16x32_bf16(
                        af[mf], bf[nf], acc[mf][nf], 0, 0, 0);
            __builtin_amdgcn_s_setprio(0);
        }
    }

    if (EPI == 0) {
        ushort* O = (ushort*)C;
#pragma unroll
        for (int mf = 0; mf < 4; ++mf) {
#pragma unroll
            for (int i = 0; i < 4; ++i) {
                int m = m0 + wr + mf*16 + lg*4 + i;
                int bq = m >> 11, t = m & (TSEQ - 1);
#pragma unroll
                for (int nf = 0; nf < 4; ++nf) {
                    int col = n0 + wc + nf*16 + lr;
                    int mat = col >> 10, hh = (col >> 6) & 15, e = col & 63;
                    float sc = (mat == 0) ? QSCALE : 1.0f;
                    O[((size_t)(mat*2*NH + bq*NH + hh))*(TSEQ*HDIM) + (size_t)t*HDIM + e] =
                        f2b(acc[mf][nf][i] * sc);
                }
            }
        }
    } else {
        float* O = (float*)C;
#pragma unroll
        for (int mf = 0; mf < 4; ++mf) {
#pragma unroll
            for (int i = 0; i < 4; ++i) {
                int m = m0 + wr + mf*16 + lg*4 + i;
#pragma unroll
                for (int nf = 0; nf < 4; ++nf) {
                    int col = n0 + wc + nf*16 + lr;
                    O[(size_t)m*DM + col] = acc[mf][nf][i] + bias[col];
                }
            }
        }
    }
}

// ---------------------------------------------------------------------------
// Causal flash attention, transposed-MFMA form. grid (T/128, B*H), block 256
// (4 waves). Wave owns 32 q-rows (2 m-frags); KV tiles of 64.
// S^T = mfma(K,Q) -> per-lane softmax (q-row local); O^T = mfma(V^T,P^T).
// qt paired (bx, 15-bx) across the two bh halves -> balanced 2 blocks/CU.
// ---------------------------------------------------------------------------
__global__ __launch_bounds__(256) void attn_mfma(const ushort* __restrict__ qkvb,
                                                 ushort* __restrict__ concatb) {
    __shared__ ushort Ks[64][72];       // [s][e]
    __shared__ ushort Vt[64][72];       // [e][s]
    __shared__ ushort Ps[4][32][72];    // per-wave P [q][k]
    const int tid = threadIdx.x;
    const int w = tid >> 6, l = tid & 63;
    const int lr = l & 15, lg = l >> 4;
    const int bh = blockIdx.y;
    const int qt = (bh >= NH) ? (15 - (int)blockIdx.x) : (int)blockIdx.x;
    const int qw0 = qt * 128 + w * 32;  // wave's first q row

    const ushort* Q = qkvb + (size_t)bh * (TSEQ*HDIM);
    const ushort* K = Q + (size_t)2*NH*TSEQ*HDIM;
    const ushort* V = K + (size_t)2*NH*TSEQ*HDIM;

    bf16x8 qf[2][2];  // [mf][kk]
#pragma unroll
    for (int mf = 0; mf < 2; ++mf)
#pragma unroll
        for (int kk = 0; kk < 2; ++kk)
            qf[mf][kk] = *reinterpret_cast<const bf16x8*>(
                &Q[(size_t)(qw0 + mf*16 + lr)*HDIM + kk*32 + lg*8]);

    f32x4 acc[2][4];                    // O^T frags: [mf(q)][nf(e)]
    float mrow[2] = {-1e30f, -1e30f}, lrow[2] = {0.f, 0.f};
#pragma unroll
    for (int mf = 0; mf < 2; ++mf)
#pragma unroll
        for (int nf = 0; nf < 4; ++nf) acc[mf][nf] = {0.f, 0.f, 0.f, 0.f};

    const int ntiles = 2*qt + 2;
    for (int jt = 0; jt < ntiles; ++jt) {
        const int s0 = jt * 64;
        __syncthreads();
        // stage K tile (64x64), vectorized
#pragma unroll
        for (int it = 0; it < 2; ++it) {
            int u = it*256 + tid;
            int row = u >> 3, c = u & 7;
            *reinterpret_cast<bf16x8*>(&Ks[row][c*8]) =
                *reinterpret_cast<const bf16x8*>(&K[(size_t)(s0+row)*HDIM + c*8]);
        }
        // stage V transposed: each wave 2 e-chunks of 8
#pragma unroll
        for (int it = 0; it < 2; ++it) {
            int cc = w*2 + it;
            BF8 vv; vv.v = *reinterpret_cast<const bf16x8*>(&V[(size_t)(s0+l)*HDIM + cc*8]);
#pragma unroll
            for (int j = 0; j < 8; ++j) Vt[cc*8 + j][l] = vv.u[j];
        }
        __syncthreads();
        if (s0 <= qw0 + 31) {
            // S^T[k][q] = K Q^T
            f32x4 sT[2][4];             // [mf(q)][nf(k)]
#pragma unroll
            for (int mf = 0; mf < 2; ++mf)
#pragma unroll
                for (int nf = 0; nf < 4; ++nf) sT[mf][nf] = {0.f, 0.f, 0.f, 0.f};
#pragma unroll
            for (int kk = 0; kk < 2; ++kk) {
                bf16x8 kf[4];
#pragma unroll
                for (int nf = 0; nf < 4; ++nf)
                    kf[nf] = *reinterpret_cast<const bf16x8*>(&Ks[nf*16 + lr][kk*32 + lg*8]);
                __builtin_amdgcn_s_setprio(1);
#pragma unroll
                for (int mf = 0; mf < 2; ++mf)
#pragma unroll
                    for (int nf = 0; nf < 4; ++nf)
                        sT[mf][nf] = __builtin_amdgcn_mfma_f32_16x16x32_bf16(
                            kf[nf], qf[mf][kk], sT[mf][nf], 0, 0, 0);
                __builtin_amdgcn_s_setprio(0);
            }
            // causal mask on diagonal region
            if (s0 + 63 > qw0) {
#pragma unroll
                for (int mf = 0; mf < 2; ++mf) {
                    int qrow = qw0 + mf*16 + lr;
#pragma unroll
                    for (int nf = 0; nf < 4; ++nf) {
                        int kbase = s0 + nf*16 + lg*4;
#pragma unroll
                        for (int i = 0; i < 4; ++i)
                            if (kbase + i > qrow) sT[mf][nf][i] = -1e30f;
                    }
                }
            }
            // per-lane online softmax (each lane owns one q-row per mf)
#pragma unroll
            for (int mf = 0; mf < 2; ++mf) {
                float tm = -1e30f;
#pragma unroll
                for (int nf = 0; nf < 4; ++nf)
#pragma unroll
                    for (int i = 0; i < 4; ++i) tm = fmaxf(tm, sT[mf][nf][i]);
                tm = fmaxf(tm, __shfl_xor(tm, 16, 64));
                tm = fmaxf(tm, __shfl_xor(tm, 32, 64));
                float mnew = fmaxf(mrow[mf], tm);
                float corr = exp2f(mrow[mf] - mnew);
                mrow[mf] = mnew;
                float ps = 0.f;
#pragma unroll
                for (int nf = 0; nf < 4; ++nf)
#pragma unroll
                    for (int i = 0; i < 4; ++i) {
                        sT[mf][nf][i] = exp2f(sT[mf][nf][i] - mnew);
                        ps += sT[mf][nf][i];
                    }
                ps += __shfl_xor(ps, 16, 64);
                ps += __shfl_xor(ps, 32, 64);
                lrow[mf] = lrow[mf]*corr + ps;
#pragma unroll
                for (int nf = 0; nf < 4; ++nf)
#pragma unroll
                    for (int i = 0; i < 4; ++i) acc[mf][nf][i] *= corr;
                // write P rows [q][k]: 4 bf16 (k..k+3) per nf -> b64 write
#pragma unroll
                for (int nf = 0; nf < 4; ++nf) {
                    union { ushort u[4]; uint2 v; } pk;
#pragma unroll
                    for (int i = 0; i < 4; ++i) pk.u[i] = f2b(sT[mf][nf][i]);
                    *reinterpret_cast<uint2*>(&Ps[w][mf*16 + lr][nf*16 + lg*4]) = pk.v;
                }
            }
            // PV: O^T += V^T P^T  (same-wave LDS, no barrier)
#pragma unroll
            for (int kk = 0; kk < 2; ++kk) {
                bf16x8 vf[4], pf[2];
#pragma unroll
                for (int nf = 0; nf < 4; ++nf)
                    vf[nf] = *reinterpret_cast<const bf16x8*>(&Vt[nf*16 + lr][kk*32 + lg*8]);
#pragma unroll
                for (int mf = 0; mf < 2; ++mf)
                    pf[mf] = *reinterpret_cast<const bf16x8*>(&Ps[w][mf*16 + lr][kk*32 + lg*8]);
                __builtin_amdgcn_s_setprio(1);
#pragma unroll
                for (int mf = 0; mf < 2; ++mf)
#pragma unroll
                    for (int nf = 0; nf < 4; ++nf)
                        acc[mf][nf] = __builtin_amdgcn_mfma_f32_16x16x32_bf16(
                            vf[nf], pf[mf], acc[mf][nf], 0, 0, 0);
                __builtin_amdgcn_s_setprio(0);
            }
        }
    }
    // epilogue: lane holds O^T[e=nf*16+lg*4+i][q=qw0+mf*16+lr]
    const int b = bh >> 4, h = bh & 15;
#pragma unroll
    for (int mf = 0; mf < 2; ++mf) {
        float inv = 1.0f / lrow[mf];
        int t = qw0 + mf*16 + lr;
        ushort* o = concatb + ((size_t)(b*TSEQ + t))*DM + h*HDIM;
#pragma unroll
        for (int nf = 0; nf < 4; ++nf) {
            union { ushort u[4]; uint2 v; } pk;
#pragma unroll
            for (int i = 0; i < 4; ++i) pk.u[i] = f2b(acc[mf][nf][i] * inv);
            *reinterpret_cast<uint2*>(&o[nf*16 + lg*4]) = pk.v;
        }
    }
}

// ---------------------------------------------------------------------------
extern "C" void kernel_launch(void* const* d_in, const int* in_sizes, int n_in,
                              void* d_out, int out_size, void* d_ws, size_t ws_size,
                              hipStream_t stream) {
    const float* x  = (const float*)d_in[0];
    const float* Wq = (const float*)d_in[1];
    const float* Wk = (const float*)d_in[2];
    const float* Wv = (const float*)d_in[3];
    const float* Wp = (const float*)d_in[4];
    const float* bp = (const float*)d_in[5];
    float* out = (float*)d_out;

    ushort* ws   = (ushort*)d_ws;
    ushort* xb   = ws;                                    // BT*DM
    ushort* wtb  = xb  + (size_t)BT*DM;                   // 3*NH*HDIM*DM (=[3072][1024])
    ushort* wpb  = wtb + (size_t)3*NH*HDIM*DM;            // DM*DM
    ushort* qkvb = wpb + (size_t)DM*DM;                   // [3][B*H][T][HD]
    ushort* cb   = qkvb + (size_t)3*2*NH*TSEQ*HDIM;       // BT*DM

    cvt_kernel<<<dim3((BT*DM/8 + 255)/256), 256, 0, stream>>>(x, xb, BT*DM/8);
    wt_kernel<<<dim3(DM/64, 3*NH), 256, 0, stream>>>(Wq, Wk, Wv, wtb);
    cvt_kernel<<<dim3(DM*DM/8/256), 256, 0, stream>>>(Wp, wpb, DM*DM/8);
    gemm_bt<0><<<dim3(BT/128, 3072/128), 256, 0, stream>>>(xb, wtb, nullptr, qkvb);
    attn_mfma<<<dim3(TSEQ/128, NB*NH), 256, 0, stream>>>(qkvb, cb);
    gemm_bt<1><<<dim3(BT/128, DM/128), 256, 0, stream>>>(cb, wpb, bp, out);
}

// Round 4
// 145.735 us; speedup vs baseline: 8.3272x; 1.1190x over previous
//
#include <hip/hip_runtime.h>
#include <hip/hip_bf16.h>

#define TSEQ 2048
#define DM   1024
#define NH   16
#define HDIM 64
#define NB   2
#define BT   (NB*TSEQ)   // 4096
// Q pre-scale: HD^-0.5 * log2(e) so softmax runs in exp2 domain
#define QSCALE 0.1803368801111204f

typedef __attribute__((ext_vector_type(8))) short bf16x8;
typedef __attribute__((ext_vector_type(4))) float f32x4;

union BF8 { bf16x8 v; ushort u[8]; };

static __device__ __forceinline__ ushort f2b(float x) {
    unsigned u = __float_as_uint(x);
    return (ushort)((u + 0x7fff + ((u >> 16) & 1)) >> 16);  // RNE, finite inputs
}

static __device__ __forceinline__ void gload16(const void* g, void* l) {
    __builtin_amdgcn_global_load_lds((const __attribute__((address_space(1))) void*)g,
                                     (__attribute__((address_space(3))) void*)l, 16, 0, 0);
}

// ---------------------------------------------------------------------------
// Prep A: f32 -> bf16 bulk convert (8 elems/thread)
// ---------------------------------------------------------------------------
__global__ __launch_bounds__(256) void cvt_kernel(const float* __restrict__ src,
                                                  ushort* __restrict__ dst, int n8) {
    int i = blockIdx.x * 256 + threadIdx.x;
    if (i >= n8) return;
    const float4* s = reinterpret_cast<const float4*>(src);
    float4 a = s[2*i], b = s[2*i+1];
    union { ushort u[8]; int4 v; } r;
    r.u[0]=f2b(a.x); r.u[1]=f2b(a.y); r.u[2]=f2b(a.z); r.u[3]=f2b(a.w);
    r.u[4]=f2b(b.x); r.u[5]=f2b(b.y); r.u[6]=f2b(b.z); r.u[7]=f2b(b.w);
    reinterpret_cast<int4*>(dst)[i] = r.v;
}

// ---------------------------------------------------------------------------
// Prep B: transpose Wq/Wk/Wv per head: f32 [D][HD] -> bf16 rows [mat][h][e][D]
// ---------------------------------------------------------------------------
__global__ __launch_bounds__(256) void wt_kernel(const float* __restrict__ Wq,
                                                 const float* __restrict__ Wk,
                                                 const float* __restrict__ Wv,
                                                 ushort* __restrict__ wtb) {
    __shared__ float tile[64][65];
    const int t = threadIdx.x;
    const int k0 = blockIdx.x * 64;
    const int mat = blockIdx.y >> 4, h = blockIdx.y & 15;
    const float* W = (mat == 0 ? Wq : (mat == 1 ? Wk : Wv)) + (size_t)h * DM * HDIM;
#pragma unroll
    for (int it = 0; it < 4; ++it) {
        int row = it*16 + (t>>4), c4 = (t&15)*4;
        float4 v = *reinterpret_cast<const float4*>(&W[(size_t)(k0+row)*HDIM + c4]);
        tile[row][c4+0]=v.x; tile[row][c4+1]=v.y; tile[row][c4+2]=v.z; tile[row][c4+3]=v.w;
    }
    __syncthreads();
    ushort* out = wtb + (size_t)(mat*NH + h) * (HDIM*DM);
#pragma unroll
    for (int it = 0; it < 4; ++it) {
        int n = it*16 + (t>>4), kc = (t&15)*4;
        union { ushort u[4]; uint2 v; } r;
#pragma unroll
        for (int j = 0; j < 4; ++j) r.u[j] = f2b(tile[kc+j][n]);
        *reinterpret_cast<uint2*>(&out[(size_t)n*DM + k0 + kc]) = r.v;
    }
}

// ---------------------------------------------------------------------------
// m97-style GEMM: C[M][N] = A[M][1024] @ B[N][1024]^T
// 128x128 tile, BK=64, 4 waves, global_load_lds w16, XCD-chunked swizzle.
// EPI 0: qkv scatter (bf16, QSCALE on mat 0). EPI 1: proj (f32 + bias).
// ---------------------------------------------------------------------------
template<int EPI>
__global__ __launch_bounds__(256) void gemm_bt(const ushort* __restrict__ A,
                                               const ushort* __restrict__ B,
                                               const float* __restrict__ bias,
                                               void* __restrict__ C) {
    __shared__ ushort As[128*64];
    __shared__ ushort Bs[128*64];
    const int tid = threadIdx.x;
    const int w = tid >> 6, l = tid & 63;
    const int lr = l & 15, lg = l >> 4;
    const int wr = (w >> 1) * 64, wc = (w & 1) * 64;
    // XCD-chunked block swizzle (gridDim.x % 8 == 0)
    const int cpx = (int)gridDim.x >> 3;
    const int wg = ((int)blockIdx.x & 7) * cpx + ((int)blockIdx.x >> 3);
    const int m0 = (wg & 31) * 128;
    const int n0 = (wg >> 5) * 128;
    const int srow = l >> 3;
    const int scol = (l & 7) * 8;

    f32x4 acc[4][4];
#pragma unroll
    for (int a = 0; a < 4; ++a)
#pragma unroll
        for (int b = 0; b < 4; ++b) acc[a][b] = {0.f, 0.f, 0.f, 0.f};

    for (int kc = 0; kc < DM/64; ++kc) {
        __syncthreads();
#pragma unroll
        for (int c = 0; c < 4; ++c) {
            int chunk = w*4 + c;
            int r = chunk*8 + srow;
            gload16(&A[(size_t)(m0+r)*DM + kc*64 + scol], &As[chunk*512]);
            gload16(&B[(size_t)(n0+r)*DM + kc*64 + scol], &Bs[chunk*512]);
        }
        __syncthreads();
#pragma unroll
        for (int kk = 0; kk < 2; ++kk) {
            bf16x8 af[4], bf[4];
#pragma unroll
            for (int mf = 0; mf < 4; ++mf)
                af[mf] = *reinterpret_cast<const bf16x8*>(&As[(wr + mf*16 + lr)*64 + kk*32 + lg*8]);
#pragma unroll
            for (int nf = 0; nf < 4; ++nf)
                bf[nf] = *reinterpret_cast<const bf16x8*>(&Bs[(wc + nf*16 + lr)*64 + kk*32 + lg*8]);
            __builtin_amdgcn_s_setprio(1);
#pragma unroll
            for (int mf = 0; mf < 4; ++mf)
#pragma unroll
                for (int nf = 0; nf < 4; ++nf)
                    acc[mf][nf] = __builtin_amdgcn_mfma_f32_16x16x32_bf16(
                        af[mf], bf[nf], acc[mf][nf], 0, 0, 0);
            __builtin_amdgcn_s_setprio(0);
        }
    }

    if (EPI == 0) {
        ushort* O = (ushort*)C;
#pragma unroll
        for (int mf = 0; mf < 4; ++mf) {
#pragma unroll
            for (int i = 0; i < 4; ++i) {
                int m = m0 + wr + mf*16 + lg*4 + i;
                int bq = m >> 11, t = m & (TSEQ - 1);
#pragma unroll
                for (int nf = 0; nf < 4; ++nf) {
                    int col = n0 + wc + nf*16 + lr;
                    int mat = col >> 10, hh = (col >> 6) & 15, e = col & 63;
                    float sc = (mat == 0) ? QSCALE : 1.0f;
                    O[((size_t)(mat*2*NH + bq*NH + hh))*(TSEQ*HDIM) + (size_t)t*HDIM + e] =
                        f2b(acc[mf][nf][i] * sc);
                }
            }
        }
    } else {
        float* O = (float*)C;
#pragma unroll
        for (int mf = 0; mf < 4; ++mf) {
#pragma unroll
            for (int i = 0; i < 4; ++i) {
                int m = m0 + wr + mf*16 + lg*4 + i;
#pragma unroll
                for (int nf = 0; nf < 4; ++nf) {
                    int col = n0 + wc + nf*16 + lr;
                    O[(size_t)m*DM + col] = acc[mf][nf][i] + bias[col];
                }
            }
        }
    }
}

// ---------------------------------------------------------------------------
// Causal flash attention. 1024 blocks x 256 thr (4 waves), q-tile 64,
// wave owns 16 q-rows -> per-lane softmax state. KV tiles 64. Pad 74 (37
// words, odd -> conflict-free b128 frags). XCD decode: each XCD owns 4
// heads (K/V 2MB -> L2-resident); largest qt dispatched first (LPT).
// ---------------------------------------------------------------------------
__global__ __launch_bounds__(256) void attn_mfma(const ushort* __restrict__ qkvb,
                                                 ushort* __restrict__ concatb) {
    __shared__ ushort Ks[64][74];       // [s][e]
    __shared__ ushort Vt[64][74];       // [e][s]
    __shared__ ushort Ps[4][16][74];    // per-wave P^T round-trip [q][k]
    const int tid = threadIdx.x;
    const int w = tid >> 6, l = tid & 63;
    const int lr = l & 15, lg = l >> 4;
    const int g = blockIdx.x;
    const int bh = (g & 7) * 4 + ((g >> 3) & 3);   // 4 heads per XCD
    const int qt = 31 - (g >> 5);                   // big blocks first
    const int qw0 = qt * 64 + w * 16;               // wave's first q row

    const ushort* Q = qkvb + (size_t)bh * (TSEQ*HDIM);
    const ushort* K = Q + (size_t)2*NH*TSEQ*HDIM;
    const ushort* V = K + (size_t)2*NH*TSEQ*HDIM;

    bf16x8 qf[2];
#pragma unroll
    for (int kk = 0; kk < 2; ++kk)
        qf[kk] = *reinterpret_cast<const bf16x8*>(&Q[(size_t)(qw0 + lr)*HDIM + kk*32 + lg*8]);

    f32x4 acc[4];
    float mrow = -3e38f, lrow = 0.f;
#pragma unroll
    for (int nf = 0; nf < 4; ++nf) acc[nf] = {0.f, 0.f, 0.f, 0.f};

    for (int jt = 0; jt <= qt; ++jt) {
        const int s0 = jt * 64;
        __syncthreads();
        // stage K tile (64x64)
#pragma unroll
        for (int it = 0; it < 2; ++it) {
            int u = it*256 + tid;
            int row = u >> 3, c = u & 7;
            *reinterpret_cast<bf16x8*>(&Ks[row][c*8]) =
                *reinterpret_cast<const bf16x8*>(&K[(size_t)(s0+row)*HDIM + c*8]);
        }
        // stage V transposed: wave w covers e in [w*16, w*16+16)
#pragma unroll
        for (int half = 0; half < 2; ++half) {
            int e0 = w*16 + half*8;
            BF8 vv; vv.v = *reinterpret_cast<const bf16x8*>(&V[(size_t)(s0+l)*HDIM + e0]);
#pragma unroll
            for (int j = 0; j < 8; ++j) Vt[e0 + j][l] = vv.u[j];
        }
        __syncthreads();

        // S^T = K Q^T : lane owns q-row (qw0+lr), k = s0 + nf*16 + lg*4 + i
        f32x4 sT[4];
#pragma unroll
        for (int nf = 0; nf < 4; ++nf) sT[nf] = {0.f, 0.f, 0.f, 0.f};
#pragma unroll
        for (int kk = 0; kk < 2; ++kk) {
            bf16x8 kf[4];
#pragma unroll
            for (int nf = 0; nf < 4; ++nf)
                kf[nf] = *reinterpret_cast<const bf16x8*>(&Ks[nf*16 + lr][kk*32 + lg*8]);
            __builtin_amdgcn_s_setprio(1);
#pragma unroll
            for (int nf = 0; nf < 4; ++nf)
                sT[nf] = __builtin_amdgcn_mfma_f32_16x16x32_bf16(kf[nf], qf[kk], sT[nf], 0, 0, 0);
            __builtin_amdgcn_s_setprio(0);
        }
        if (jt == qt) {                 // diagonal tile: causal mask
            int qrow = qw0 + lr;
#pragma unroll
            for (int nf = 0; nf < 4; ++nf) {
                int kbase = s0 + nf*16 + lg*4;
#pragma unroll
                for (int i = 0; i < 4; ++i)
                    if (kbase + i > qrow) sT[nf][i] = -1e30f;
            }
        }
        // per-lane online softmax with deferred rescale (THR=8 in exp2 domain)
        float tm = -3e38f;
#pragma unroll
        for (int nf = 0; nf < 4; ++nf)
#pragma unroll
            for (int i = 0; i < 4; ++i) tm = fmaxf(tm, sT[nf][i]);
        tm = fmaxf(tm, __shfl_xor(tm, 16, 64));
        tm = fmaxf(tm, __shfl_xor(tm, 32, 64));
        if (__any(tm > mrow + 8.0f)) {
            float mnew = fmaxf(mrow, tm);
            float corr = exp2f(mrow - mnew);
            lrow *= corr;
#pragma unroll
            for (int nf = 0; nf < 4; ++nf)
#pragma unroll
                for (int i = 0; i < 4; ++i) acc[nf][i] *= corr;
            mrow = mnew;
        }
        float ps = 0.f;
#pragma unroll
        for (int nf = 0; nf < 4; ++nf)
#pragma unroll
            for (int i = 0; i < 4; ++i) {
                sT[nf][i] = exp2f(sT[nf][i] - mrow);
                ps += sT[nf][i];
            }
        ps += __shfl_xor(ps, 16, 64);
        ps += __shfl_xor(ps, 32, 64);
        lrow += ps;
        // P^T -> per-wave LDS (b64 writes), reread as B-frags (same wave)
#pragma unroll
        for (int nf = 0; nf < 4; ++nf) {
            union { ushort u[4]; uint2 v; } pk;
#pragma unroll
            for (int i = 0; i < 4; ++i) pk.u[i] = f2b(sT[nf][i]);
            *reinterpret_cast<uint2*>(&Ps[w][lr][nf*16 + lg*4]) = pk.v;
        }
        // O^T += V^T P^T
#pragma unroll
        for (int kk = 0; kk < 2; ++kk) {
            bf16x8 vf[4];
#pragma unroll
            for (int nf = 0; nf < 4; ++nf)
                vf[nf] = *reinterpret_cast<const bf16x8*>(&Vt[nf*16 + lr][kk*32 + lg*8]);
            bf16x8 pf = *reinterpret_cast<const bf16x8*>(&Ps[w][lr][kk*32 + lg*8]);
            __builtin_amdgcn_s_setprio(1);
#pragma unroll
            for (int nf = 0; nf < 4; ++nf)
                acc[nf] = __builtin_amdgcn_mfma_f32_16x16x32_bf16(vf[nf], pf, acc[nf], 0, 0, 0);
            __builtin_amdgcn_s_setprio(0);
        }
    }
    // epilogue: lane holds O^T[e = nf*16+lg*4+i][q = qw0+lr]
    const int b = bh >> 4, h = bh & 15;
    float inv = 1.0f / lrow;
    int t = qw0 + lr;
    ushort* o = concatb + ((size_t)(b*TSEQ + t))*DM + h*HDIM;
#pragma unroll
    for (int nf = 0; nf < 4; ++nf) {
        union { ushort u[4]; uint2 v; } pk;
#pragma unroll
        for (int i = 0; i < 4; ++i) pk.u[i] = f2b(acc[nf][i] * inv);
        *reinterpret_cast<uint2*>(&o[nf*16 + lg*4]) = pk.v;
    }
}

// ---------------------------------------------------------------------------
extern "C" void kernel_launch(void* const* d_in, const int* in_sizes, int n_in,
                              void* d_out, int out_size, void* d_ws, size_t ws_size,
                              hipStream_t stream) {
    const float* x  = (const float*)d_in[0];
    const float* Wq = (const float*)d_in[1];
    const float* Wk = (const float*)d_in[2];
    const float* Wv = (const float*)d_in[3];
    const float* Wp = (const float*)d_in[4];
    const float* bp = (const float*)d_in[5];
    float* out = (float*)d_out;

    ushort* ws   = (ushort*)d_ws;
    ushort* xb   = ws;                                    // BT*DM
    ushort* wtb  = xb  + (size_t)BT*DM;                   // [3072][1024]
    ushort* wpb  = wtb + (size_t)3*NH*HDIM*DM;            // DM*DM
    ushort* qkvb = wpb + (size_t)DM*DM;                   // [3][B*H][T][HD]
    ushort* cb   = qkvb + (size_t)3*2*NH*TSEQ*HDIM;       // BT*DM

    cvt_kernel<<<dim3((BT*DM/8 + 255)/256), 256, 0, stream>>>(x, xb, BT*DM/8);
    wt_kernel<<<dim3(DM/64, 3*NH), 256, 0, stream>>>(Wq, Wk, Wv, wtb);
    cvt_kernel<<<dim3(DM*DM/8/256), 256, 0, stream>>>(Wp, wpb, DM*DM/8);
    gemm_bt<0><<<dim3(32*24), 256, 0, stream>>>(xb, wtb, nullptr, qkvb);
    attn_mfma<<<dim3(1024), 256, 0, stream>>>(qkvb, cb);
    gemm_bt<1><<<dim3(32*8), 256, 0, stream>>>(cb, wpb, bp, out);
}

// Round 5
// 143.814 us; speedup vs baseline: 8.4384x; 1.0134x over previous
//
#include <hip/hip_runtime.h>
#include <hip/hip_bf16.h>

#define TSEQ 2048
#define DM   1024
#define NH   16
#define HDIM 64
#define NB   2
#define BT   (NB*TSEQ)   // 4096
// Q pre-scale: HD^-0.5 * log2(e) so softmax runs in exp2 domain
#define QSCALE 0.1803368801111204f

typedef __attribute__((ext_vector_type(8))) short bf16x8;
typedef __attribute__((ext_vector_type(4))) float f32x4;

union BF8 { bf16x8 v; ushort u[8]; };

static __device__ __forceinline__ ushort f2b(float x) {
    unsigned u = __float_as_uint(x);
    return (ushort)((u + 0x7fff + ((u >> 16) & 1)) >> 16);  // RNE, finite inputs
}

static __device__ __forceinline__ void gload16(const void* g, void* l) {
    __builtin_amdgcn_global_load_lds((const __attribute__((address_space(1))) void*)g,
                                     (__attribute__((address_space(3))) void*)l, 16, 0, 0);
}

// ---------------------------------------------------------------------------
// Prep A: f32 -> bf16 bulk convert (8 elems/thread)
// ---------------------------------------------------------------------------
__global__ __launch_bounds__(256) void cvt_kernel(const float* __restrict__ src,
                                                  ushort* __restrict__ dst, int n8) {
    int i = blockIdx.x * 256 + threadIdx.x;
    if (i >= n8) return;
    const float4* s = reinterpret_cast<const float4*>(src);
    float4 a = s[2*i], b = s[2*i+1];
    union { ushort u[8]; int4 v; } r;
    r.u[0]=f2b(a.x); r.u[1]=f2b(a.y); r.u[2]=f2b(a.z); r.u[3]=f2b(a.w);
    r.u[4]=f2b(b.x); r.u[5]=f2b(b.y); r.u[6]=f2b(b.z); r.u[7]=f2b(b.w);
    reinterpret_cast<int4*>(dst)[i] = r.v;
}

// ---------------------------------------------------------------------------
// Prep B: transpose Wq/Wk/Wv per head: f32 [D][HD] -> bf16 rows [mat][h][e][D]
// ---------------------------------------------------------------------------
__global__ __launch_bounds__(256) void wt_kernel(const float* __restrict__ Wq,
                                                 const float* __restrict__ Wk,
                                                 const float* __restrict__ Wv,
                                                 ushort* __restrict__ wtb) {
    __shared__ float tile[64][65];
    const int t = threadIdx.x;
    const int k0 = blockIdx.x * 64;
    const int mat = blockIdx.y >> 4, h = blockIdx.y & 15;
    const float* W = (mat == 0 ? Wq : (mat == 1 ? Wk : Wv)) + (size_t)h * DM * HDIM;
#pragma unroll
    for (int it = 0; it < 4; ++it) {
        int row = it*16 + (t>>4), c4 = (t&15)*4;
        float4 v = *reinterpret_cast<const float4*>(&W[(size_t)(k0+row)*HDIM + c4]);
        tile[row][c4+0]=v.x; tile[row][c4+1]=v.y; tile[row][c4+2]=v.z; tile[row][c4+3]=v.w;
    }
    __syncthreads();
    ushort* out = wtb + (size_t)(mat*NH + h) * (HDIM*DM);
#pragma unroll
    for (int it = 0; it < 4; ++it) {
        int n = it*16 + (t>>4), kc = (t&15)*4;
        union { ushort u[4]; uint2 v; } r;
#pragma unroll
        for (int j = 0; j < 4; ++j) r.u[j] = f2b(tile[kc+j][n]);
        *reinterpret_cast<uint2*>(&out[(size_t)n*DM + k0 + kc]) = r.v;
    }
}

// ---------------------------------------------------------------------------
// m97-style GEMM: C[M][N] = A[M][1024] @ B[N][1024]^T
// 128x128 tile, BK=64, 4 waves, global_load_lds w16, XCD-chunked swizzle.
// EPI 0: qkv scatter (bf16, QSCALE on mat 0). EPI 1: proj (f32 + bias).
// ---------------------------------------------------------------------------
template<int EPI>
__global__ __launch_bounds__(256) void gemm_bt(const ushort* __restrict__ A,
                                               const ushort* __restrict__ B,
                                               const float* __restrict__ bias,
                                               void* __restrict__ C) {
    __shared__ ushort As[128*64];
    __shared__ ushort Bs[128*64];
    const int tid = threadIdx.x;
    const int w = tid >> 6, l = tid & 63;
    const int lr = l & 15, lg = l >> 4;
    const int wr = (w >> 1) * 64, wc = (w & 1) * 64;
    const int cpx = (int)gridDim.x >> 3;
    const int wg = ((int)blockIdx.x & 7) * cpx + ((int)blockIdx.x >> 3);
    const int m0 = (wg & 31) * 128;
    const int n0 = (wg >> 5) * 128;
    const int srow = l >> 3;
    const int scol = (l & 7) * 8;

    f32x4 acc[4][4];
#pragma unroll
    for (int a = 0; a < 4; ++a)
#pragma unroll
        for (int b = 0; b < 4; ++b) acc[a][b] = {0.f, 0.f, 0.f, 0.f};

    for (int kc = 0; kc < DM/64; ++kc) {
        __syncthreads();
#pragma unroll
        for (int c = 0; c < 4; ++c) {
            int chunk = w*4 + c;
            int r = chunk*8 + srow;
            gload16(&A[(size_t)(m0+r)*DM + kc*64 + scol], &As[chunk*512]);
            gload16(&B[(size_t)(n0+r)*DM + kc*64 + scol], &Bs[chunk*512]);
        }
        __syncthreads();
#pragma unroll
        for (int kk = 0; kk < 2; ++kk) {
            bf16x8 af[4], bf[4];
#pragma unroll
            for (int mf = 0; mf < 4; ++mf)
                af[mf] = *reinterpret_cast<const bf16x8*>(&As[(wr + mf*16 + lr)*64 + kk*32 + lg*8]);
#pragma unroll
            for (int nf = 0; nf < 4; ++nf)
                bf[nf] = *reinterpret_cast<const bf16x8*>(&Bs[(wc + nf*16 + lr)*64 + kk*32 + lg*8]);
            __builtin_amdgcn_s_setprio(1);
#pragma unroll
            for (int mf = 0; mf < 4; ++mf)
#pragma unroll
                for (int nf = 0; nf < 4; ++nf)
                    acc[mf][nf] = __builtin_amdgcn_mfma_f32_16x16x32_bf16(
                        af[mf], bf[nf], acc[mf][nf], 0, 0, 0);
            __builtin_amdgcn_s_setprio(0);
        }
    }

    if (EPI == 0) {
        ushort* O = (ushort*)C;
#pragma unroll
        for (int mf = 0; mf < 4; ++mf) {
#pragma unroll
            for (int i = 0; i < 4; ++i) {
                int m = m0 + wr + mf*16 + lg*4 + i;
                int bq = m >> 11, t = m & (TSEQ - 1);
#pragma unroll
                for (int nf = 0; nf < 4; ++nf) {
                    int col = n0 + wc + nf*16 + lr;
                    int mat = col >> 10, hh = (col >> 6) & 15, e = col & 63;
                    float sc = (mat == 0) ? QSCALE : 1.0f;
                    O[((size_t)(mat*2*NH + bq*NH + hh))*(TSEQ*HDIM) + (size_t)t*HDIM + e] =
                        f2b(acc[mf][nf][i] * sc);
                }
            }
        }
    } else {
        float* O = (float*)C;
#pragma unroll
        for (int mf = 0; mf < 4; ++mf) {
#pragma unroll
            for (int i = 0; i < 4; ++i) {
                int m = m0 + wr + mf*16 + lg*4 + i;
#pragma unroll
                for (int nf = 0; nf < 4; ++nf) {
                    int col = n0 + wc + nf*16 + lr;
                    O[(size_t)m*DM + col] = acc[mf][nf][i] + bias[col];
                }
            }
        }
    }
}

// ---------------------------------------------------------------------------
// Causal flash attention, paired q-tiles. 512 blocks x 256 thr (4 waves).
// Block (bh, p) owns q-tiles qtHI=16+p and qtLO=15-p: uniform 33 MFMA-tiles.
// kf/vf fragments shared between both q-subtiles. K staged via DMA with
// pre-swizzled source (linear dest, chunk^=(row&7) on src & read). Vt/Ps
// same XOR swizzle, unpadded. Double-buffered staging, 1 barrier/tile.
// ---------------------------------------------------------------------------
__global__ __launch_bounds__(256) void attn_mfma(const ushort* __restrict__ qkvb,
                                                 ushort* __restrict__ concatb) {
    __shared__ ushort Ks[2][64*64];
    __shared__ ushort Vt[2][64*64];     // [e][s], swizzled
    __shared__ ushort Ps[4][32*64];     // per-wave P^T rows: 0-15 HI, 16-31 LO
    const int tid = threadIdx.x;
    const int w = tid >> 6, l = tid & 63;
    const int lr = l & 15, lg = l >> 4;
    const int g = blockIdx.x;
    const int bh = (g & 7) * 4 + ((g >> 3) & 3);   // 4 heads per XCD
    const int p  = g >> 5;                          // pair index 0..15
    const int qtHI = 16 + p, qtLO = 15 - p;
    const int qH0 = qtHI * 64 + w * 16;             // wave's HI q rows
    const int qL0 = qtLO * 64 + w * 16;             // wave's LO q rows

    const ushort* Q = qkvb + (size_t)bh * (TSEQ*HDIM);
    const ushort* K = Q + (size_t)2*NH*TSEQ*HDIM;
    const ushort* V = K + (size_t)2*NH*TSEQ*HDIM;

    bf16x8 qfH[2], qfL[2];
#pragma unroll
    for (int kk = 0; kk < 2; ++kk) {
        qfH[kk] = *reinterpret_cast<const bf16x8*>(&Q[(size_t)(qH0 + lr)*HDIM + kk*32 + lg*8]);
        qfL[kk] = *reinterpret_cast<const bf16x8*>(&Q[(size_t)(qL0 + lr)*HDIM + kk*32 + lg*8]);
    }

    f32x4 accH[4], accL[4];
    float mH = -3e38f, lH = 0.f, mL = -3e38f, lL = 0.f;
#pragma unroll
    for (int nf = 0; nf < 4; ++nf) { accH[nf] = {0.f,0.f,0.f,0.f}; accL[nf] = {0.f,0.f,0.f,0.f}; }

    ushort* PsW = &Ps[w][0];
    const int krow = tid >> 3, kchunk = (tid & 7) ^ ((tid >> 3) & 7);

    // ---- prologue: stage tile 0 into buf 0 ----
    {
#pragma unroll
        for (int it = 0; it < 2; ++it)
            gload16(&K[(size_t)(it*32 + krow)*HDIM + kchunk*8], &Ks[0][it*2048 + tid*8]);
        BF8 a, b;
        a.v = *reinterpret_cast<const bf16x8*>(&V[(size_t)l*HDIM + w*16]);
        b.v = *reinterpret_cast<const bf16x8*>(&V[(size_t)l*HDIM + w*16 + 8]);
#pragma unroll
        for (int j = 0; j < 8; ++j) {
            Vt[0][(w*16 + j)*64 + ((l>>3) ^ j)*8 + (l&7)] = a.u[j];
            Vt[0][(w*16 + 8 + j)*64 + ((l>>3) ^ j)*8 + (l&7)] = b.u[j];
        }
        __syncthreads();
    }

    int cur = 0;
    for (int jt = 0; jt <= qtHI; ++jt) {
        const int nxt = cur ^ 1;
        const int s0 = jt * 64;
        const bool pref = (jt < qtHI);
        const bool loAct = (jt <= qtLO);
        BF8 ga, gb;
        if (pref) {
            const int s0n = s0 + 64;
#pragma unroll
            for (int it = 0; it < 2; ++it)
                gload16(&K[(size_t)(s0n + it*32 + krow)*HDIM + kchunk*8], &Ks[nxt][it*2048 + tid*8]);
            ga.v = *reinterpret_cast<const bf16x8*>(&V[(size_t)(s0n + l)*HDIM + w*16]);
            gb.v = *reinterpret_cast<const bf16x8*>(&V[(size_t)(s0n + l)*HDIM + w*16 + 8]);
        }

        // ---- QK^T (kf shared by HI/LO) ----
        f32x4 sH[4], sL[4];
#pragma unroll
        for (int nf = 0; nf < 4; ++nf) { sH[nf] = {0.f,0.f,0.f,0.f}; sL[nf] = {0.f,0.f,0.f,0.f}; }
#pragma unroll
        for (int kk = 0; kk < 2; ++kk) {
            bf16x8 kf[4];
#pragma unroll
            for (int nf = 0; nf < 4; ++nf)
                kf[nf] = *reinterpret_cast<const bf16x8*>(
                    &Ks[cur][(nf*16 + lr)*64 + ((kk*4 + lg) ^ (lr&7))*8]);
            __builtin_amdgcn_s_setprio(1);
#pragma unroll
            for (int nf = 0; nf < 4; ++nf)
                sH[nf] = __builtin_amdgcn_mfma_f32_16x16x32_bf16(kf[nf], qfH[kk], sH[nf], 0, 0, 0);
            if (loAct) {
#pragma unroll
                for (int nf = 0; nf < 4; ++nf)
                    sL[nf] = __builtin_amdgcn_mfma_f32_16x16x32_bf16(kf[nf], qfL[kk], sL[nf], 0, 0, 0);
            }
            __builtin_amdgcn_s_setprio(0);
        }

        // ---- softmax HI ----
        {
            if (jt == qtHI) {
                int qrow = qH0 + lr;
#pragma unroll
                for (int nf = 0; nf < 4; ++nf) {
                    int kbase = s0 + nf*16 + lg*4;
#pragma unroll
                    for (int i = 0; i < 4; ++i)
                        if (kbase + i > qrow) sH[nf][i] = -1e30f;
                }
            }
            float tm = -3e38f;
#pragma unroll
            for (int nf = 0; nf < 4; ++nf)
#pragma unroll
                for (int i = 0; i < 4; ++i) tm = fmaxf(tm, sH[nf][i]);
            tm = fmaxf(tm, __shfl_xor(tm, 16, 64));
            tm = fmaxf(tm, __shfl_xor(tm, 32, 64));
            if (__any(tm > mH + 8.0f)) {
                float mnew = fmaxf(mH, tm);
                float corr = exp2f(mH - mnew);
                lH *= corr;
#pragma unroll
                for (int nf = 0; nf < 4; ++nf)
#pragma unroll
                    for (int i = 0; i < 4; ++i) accH[nf][i] *= corr;
                mH = mnew;
            }
            float ps = 0.f;
#pragma unroll
            for (int nf = 0; nf < 4; ++nf)
#pragma unroll
                for (int i = 0; i < 4; ++i) { sH[nf][i] = exp2f(sH[nf][i] - mH); ps += sH[nf][i]; }
            ps += __shfl_xor(ps, 16, 64);
            ps += __shfl_xor(ps, 32, 64);
            lH += ps;
#pragma unroll
            for (int nf = 0; nf < 4; ++nf) {
                union { ushort u[4]; uint2 v; } pk;
#pragma unroll
                for (int i = 0; i < 4; ++i) pk.u[i] = f2b(sH[nf][i]);
                *reinterpret_cast<uint2*>(
                    &PsW[lr*64 + ((2*nf + (lg>>1)) ^ (lr&7))*8 + (lg&1)*4]) = pk.v;
            }
        }
        // ---- softmax LO ----
        if (loAct) {
            if (jt == qtLO) {
                int qrow = qL0 + lr;
#pragma unroll
                for (int nf = 0; nf < 4; ++nf) {
                    int kbase = s0 + nf*16 + lg*4;
#pragma unroll
                    for (int i = 0; i < 4; ++i)
                        if (kbase + i > qrow) sL[nf][i] = -1e30f;
                }
            }
            float tm = -3e38f;
#pragma unroll
            for (int nf = 0; nf < 4; ++nf)
#pragma unroll
                for (int i = 0; i < 4; ++i) tm = fmaxf(tm, sL[nf][i]);
            tm = fmaxf(tm, __shfl_xor(tm, 16, 64));
            tm = fmaxf(tm, __shfl_xor(tm, 32, 64));
            if (__any(tm > mL + 8.0f)) {
                float mnew = fmaxf(mL, tm);
                float corr = exp2f(mL - mnew);
                lL *= corr;
#pragma unroll
                for (int nf = 0; nf < 4; ++nf)
#pragma unroll
                    for (int i = 0; i < 4; ++i) accL[nf][i] *= corr;
                mL = mnew;
            }
            float ps = 0.f;
#pragma unroll
            for (int nf = 0; nf < 4; ++nf)
#pragma unroll
                for (int i = 0; i < 4; ++i) { sL[nf][i] = exp2f(sL[nf][i] - mL); ps += sL[nf][i]; }
            ps += __shfl_xor(ps, 16, 64);
            ps += __shfl_xor(ps, 32, 64);
            lL += ps;
#pragma unroll
            for (int nf = 0; nf < 4; ++nf) {
                union { ushort u[4]; uint2 v; } pk;
#pragma unroll
                for (int i = 0; i < 4; ++i) pk.u[i] = f2b(sL[nf][i]);
                *reinterpret_cast<uint2*>(
                    &PsW[(16 + lr)*64 + ((2*nf + (lg>>1)) ^ (lr&7))*8 + (lg&1)*4]) = pk.v;
            }
        }

        // ---- PV (vf shared by HI/LO) ----
#pragma unroll
        for (int kk = 0; kk < 2; ++kk) {
            bf16x8 vf[4];
#pragma unroll
            for (int nf = 0; nf < 4; ++nf)
                vf[nf] = *reinterpret_cast<const bf16x8*>(
                    &Vt[cur][(nf*16 + lr)*64 + ((kk*4 + lg) ^ (lr&7))*8]);
            bf16x8 pfH = *reinterpret_cast<const bf16x8*>(
                &PsW[lr*64 + ((kk*4 + lg) ^ (lr&7))*8]);
            __builtin_amdgcn_s_setprio(1);
#pragma unroll
            for (int nf = 0; nf < 4; ++nf)
                accH[nf] = __builtin_amdgcn_mfma_f32_16x16x32_bf16(vf[nf], pfH, accH[nf], 0, 0, 0);
            __builtin_amdgcn_s_setprio(0);
            if (loAct) {
                bf16x8 pfL = *reinterpret_cast<const bf16x8*>(
                    &PsW[(16 + lr)*64 + ((kk*4 + lg) ^ (lr&7))*8]);
                __builtin_amdgcn_s_setprio(1);
#pragma unroll
                for (int nf = 0; nf < 4; ++nf)
                    accL[nf] = __builtin_amdgcn_mfma_f32_16x16x32_bf16(vf[nf], pfL, accL[nf], 0, 0, 0);
                __builtin_amdgcn_s_setprio(0);
            }
        }

        // ---- finish staging next tile's V (loads issued at top) ----
        if (pref) {
#pragma unroll
            for (int j = 0; j < 8; ++j) {
                Vt[nxt][(w*16 + j)*64 + ((l>>3) ^ j)*8 + (l&7)] = ga.u[j];
                Vt[nxt][(w*16 + 8 + j)*64 + ((l>>3) ^ j)*8 + (l&7)] = gb.u[j];
            }
        }
        __syncthreads();
        cur = nxt;
    }

    // ---- epilogue: lane holds O^T[e = nf*16+lg*4+i][q = q?0+lr] ----
    const int b = bh >> 4, h = bh & 15;
    {
        float inv = 1.0f / lH;
        int t = qH0 + lr;
        ushort* o = concatb + ((size_t)(b*TSEQ + t))*DM + h*HDIM;
#pragma unroll
        for (int nf = 0; nf < 4; ++nf) {
            union { ushort u[4]; uint2 v; } pk;
#pragma unroll
            for (int i = 0; i < 4; ++i) pk.u[i] = f2b(accH[nf][i] * inv);
            *reinterpret_cast<uint2*>(&o[nf*16 + lg*4]) = pk.v;
        }
    }
    {
        float inv = 1.0f / lL;
        int t = qL0 + lr;
        ushort* o = concatb + ((size_t)(b*TSEQ + t))*DM + h*HDIM;
#pragma unroll
        for (int nf = 0; nf < 4; ++nf) {
            union { ushort u[4]; uint2 v; } pk;
#pragma unroll
            for (int i = 0; i < 4; ++i) pk.u[i] = f2b(accL[nf][i] * inv);
            *reinterpret_cast<uint2*>(&o[nf*16 + lg*4]) = pk.v;
        }
    }
}

// ---------------------------------------------------------------------------
extern "C" void kernel_launch(void* const* d_in, const int* in_sizes, int n_in,
                              void* d_out, int out_size, void* d_ws, size_t ws_size,
                              hipStream_t stream) {
    const float* x  = (const float*)d_in[0];
    const float* Wq = (const float*)d_in[1];
    const float* Wk = (const float*)d_in[2];
    const float* Wv = (const float*)d_in[3];
    const float* Wp = (const float*)d_in[4];
    const float* bp = (const float*)d_in[5];
    float* out = (float*)d_out;

    ushort* ws   = (ushort*)d_ws;
    ushort* xb   = ws;                                    // BT*DM
    ushort* wtb  = xb  + (size_t)BT*DM;                   // [3072][1024]
    ushort* wpb  = wtb + (size_t)3*NH*HDIM*DM;            // DM*DM
    ushort* qkvb = wpb + (size_t)DM*DM;                   // [3][B*H][T][HD]
    ushort* cb   = qkvb + (size_t)3*2*NH*TSEQ*HDIM;       // BT*DM

    cvt_kernel<<<dim3((BT*DM/8 + 255)/256), 256, 0, stream>>>(x, xb, BT*DM/8);
    wt_kernel<<<dim3(DM/64, 3*NH), 256, 0, stream>>>(Wq, Wk, Wv, wtb);
    cvt_kernel<<<dim3(DM*DM/8/256), 256, 0, stream>>>(Wp, wpb, DM*DM/8);
    gemm_bt<0><<<dim3(32*24), 256, 0, stream>>>(xb, wtb, nullptr, qkvb);
    attn_mfma<<<dim3(512), 256, 0, stream>>>(qkvb, cb);
    gemm_bt<1><<<dim3(32*8), 256, 0, stream>>>(cb, wpb, bp, out);
}

// Round 7
// 141.125 us; speedup vs baseline: 8.5992x; 1.0191x over previous
//
#include <hip/hip_runtime.h>
#include <hip/hip_bf16.h>

#define TSEQ 2048
#define DM   1024
#define NH   16
#define HDIM 64
#define NB   2
#define BT   (NB*TSEQ)   // 4096
// Q pre-scale: HD^-0.5 * log2(e) so softmax runs in exp2 domain
#define QSCALE 0.1803368801111204f

typedef __attribute__((ext_vector_type(8))) short bf16x8;
typedef __attribute__((ext_vector_type(4))) float f32x4;

union BF8 { bf16x8 v; ushort u[8]; };

static __device__ __forceinline__ ushort f2b(float x) {
    unsigned u = __float_as_uint(x);
    return (ushort)((u + 0x7fff + ((u >> 16) & 1)) >> 16);  // RNE, finite inputs
}

static __device__ __forceinline__ unsigned cvtpk(float lo, float hi) {
    unsigned r;
    asm("v_cvt_pk_bf16_f32 %0, %1, %2" : "=v"(r) : "v"(lo), "v"(hi));
    return r;
}

static __device__ __forceinline__ float fmax3(float a, float b, float c) {
    return fmaxf(fmaxf(a, b), c);   // clang fuses to v_max3_f32
}

static __device__ __forceinline__ void gload16(const void* g, void* l) {
    __builtin_amdgcn_global_load_lds((const __attribute__((address_space(1))) void*)g,
                                     (__attribute__((address_space(3))) void*)l, 16, 0, 0);
}

// ---------------------------------------------------------------------------
// Prep A: f32 -> bf16 bulk convert (8 elems/thread)
// ---------------------------------------------------------------------------
__global__ __launch_bounds__(256) void cvt_kernel(const float* __restrict__ src,
                                                  ushort* __restrict__ dst, int n8) {
    int i = blockIdx.x * 256 + threadIdx.x;
    if (i >= n8) return;
    const float4* s = reinterpret_cast<const float4*>(src);
    float4 a = s[2*i], b = s[2*i+1];
    union { ushort u[8]; int4 v; } r;
    r.u[0]=f2b(a.x); r.u[1]=f2b(a.y); r.u[2]=f2b(a.z); r.u[3]=f2b(a.w);
    r.u[4]=f2b(b.x); r.u[5]=f2b(b.y); r.u[6]=f2b(b.z); r.u[7]=f2b(b.w);
    reinterpret_cast<int4*>(dst)[i] = r.v;
}

// ---------------------------------------------------------------------------
// Prep B: transpose Wq/Wk/Wv per head: f32 [D][HD] -> bf16 rows [mat][h][e][D]
// ---------------------------------------------------------------------------
__global__ __launch_bounds__(256) void wt_kernel(const float* __restrict__ Wq,
                                                 const float* __restrict__ Wk,
                                                 const float* __restrict__ Wv,
                                                 ushort* __restrict__ wtb) {
    __shared__ float tile[64][65];
    const int t = threadIdx.x;
    const int k0 = blockIdx.x * 64;
    const int mat = blockIdx.y >> 4, h = blockIdx.y & 15;
    const float* W = (mat == 0 ? Wq : (mat == 1 ? Wk : Wv)) + (size_t)h * DM * HDIM;
#pragma unroll
    for (int it = 0; it < 4; ++it) {
        int row = it*16 + (t>>4), c4 = (t&15)*4;
        float4 v = *reinterpret_cast<const float4*>(&W[(size_t)(k0+row)*HDIM + c4]);
        tile[row][c4+0]=v.x; tile[row][c4+1]=v.y; tile[row][c4+2]=v.z; tile[row][c4+3]=v.w;
    }
    __syncthreads();
    ushort* out = wtb + (size_t)(mat*NH + h) * (HDIM*DM);
#pragma unroll
    for (int it = 0; it < 4; ++it) {
        int n = it*16 + (t>>4), kc = (t&15)*4;
        union { ushort u[4]; uint2 v; } r;
#pragma unroll
        for (int j = 0; j < 4; ++j) r.u[j] = f2b(tile[kc+j][n]);
        *reinterpret_cast<uint2*>(&out[(size_t)n*DM + k0 + kc]) = r.v;
    }
}

// ---------------------------------------------------------------------------
// m97-style GEMM: C[M][N] = A[M][1024] @ B[N][1024]^T
// 128x128 tile, BK=64, 4 waves, global_load_lds w16, XCD-chunked swizzle.
// EPI 0: qkv scatter (bf16, QSCALE on mat 0). EPI 1: proj (f32 + bias).
// ---------------------------------------------------------------------------
template<int EPI>
__global__ __launch_bounds__(256) void gemm_bt(const ushort* __restrict__ A,
                                               const ushort* __restrict__ B,
                                               const float* __restrict__ bias,
                                               void* __restrict__ C) {
    __shared__ ushort As[128*64];
    __shared__ ushort Bs[128*64];
    const int tid = threadIdx.x;
    const int w = tid >> 6, l = tid & 63;
    const int lr = l & 15, lg = l >> 4;
    const int wr = (w >> 1) * 64, wc = (w & 1) * 64;
    const int cpx = (int)gridDim.x >> 3;
    const int wg = ((int)blockIdx.x & 7) * cpx + ((int)blockIdx.x >> 3);
    const int m0 = (wg & 31) * 128;
    const int n0 = (wg >> 5) * 128;
    const int srow = l >> 3;
    const int scol = (l & 7) * 8;

    f32x4 acc[4][4];
#pragma unroll
    for (int a = 0; a < 4; ++a)
#pragma unroll
        for (int b = 0; b < 4; ++b) acc[a][b] = {0.f, 0.f, 0.f, 0.f};

    for (int kc = 0; kc < DM/64; ++kc) {
        __syncthreads();
#pragma unroll
        for (int c = 0; c < 4; ++c) {
            int chunk = w*4 + c;
            int r = chunk*8 + srow;
            gload16(&A[(size_t)(m0+r)*DM + kc*64 + scol], &As[chunk*512]);
            gload16(&B[(size_t)(n0+r)*DM + kc*64 + scol], &Bs[chunk*512]);
        }
        __syncthreads();
#pragma unroll
        for (int kk = 0; kk < 2; ++kk) {
            bf16x8 af[4], bf[4];
#pragma unroll
            for (int mf = 0; mf < 4; ++mf)
                af[mf] = *reinterpret_cast<const bf16x8*>(&As[(wr + mf*16 + lr)*64 + kk*32 + lg*8]);
#pragma unroll
            for (int nf = 0; nf < 4; ++nf)
                bf[nf] = *reinterpret_cast<const bf16x8*>(&Bs[(wc + nf*16 + lr)*64 + kk*32 + lg*8]);
            __builtin_amdgcn_s_setprio(1);
#pragma unroll
            for (int mf = 0; mf < 4; ++mf)
#pragma unroll
                for (int nf = 0; nf < 4; ++nf)
                    acc[mf][nf] = __builtin_amdgcn_mfma_f32_16x16x32_bf16(
                        af[mf], bf[nf], acc[mf][nf], 0, 0, 0);
            __builtin_amdgcn_s_setprio(0);
        }
    }

    if (EPI == 0) {
        ushort* O = (ushort*)C;
#pragma unroll
        for (int mf = 0; mf < 4; ++mf) {
#pragma unroll
            for (int i = 0; i < 4; ++i) {
                int m = m0 + wr + mf*16 + lg*4 + i;
                int bq = m >> 11, t = m & (TSEQ - 1);
#pragma unroll
                for (int nf = 0; nf < 4; ++nf) {
                    int col = n0 + wc + nf*16 + lr;
                    int mat = col >> 10, hh = (col >> 6) & 15, e = col & 63;
                    float sc = (mat == 0) ? QSCALE : 1.0f;
                    O[((size_t)(mat*2*NH + bq*NH + hh))*(TSEQ*HDIM) + (size_t)t*HDIM + e] =
                        f2b(acc[mf][nf][i] * sc);
                }
            }
        }
    } else {
        float* O = (float*)C;
#pragma unroll
        for (int mf = 0; mf < 4; ++mf) {
#pragma unroll
            for (int i = 0; i < 4; ++i) {
                int m = m0 + wr + mf*16 + lg*4 + i;
#pragma unroll
                for (int nf = 0; nf < 4; ++nf) {
                    int col = n0 + wc + nf*16 + lr;
                    O[(size_t)m*DM + col] = acc[mf][nf][i] + bias[col];
                }
            }
        }
    }
}

// ---------------------------------------------------------------------------
// Causal flash attention, paired q-tiles. 512 blocks x 256 thr (4 waves).
// Block (bh,p) owns q-tiles 16+p and 15-p (uniform 33 subtile-iters).
// K: DMA, row-major XOR-swizzled (src-preswizzle + read-xor).
// V: reg-staged transpose-scatter into XOR-swizzled [e][s] (loads issued
//    early, writes after PV = T14 split). P: cvt_pk pack -> per-wave LDS.
// ---------------------------------------------------------------------------
__global__ __launch_bounds__(256) void attn_mfma(const ushort* __restrict__ qkvb,
                                                 ushort* __restrict__ concatb) {
    __shared__ ushort Ks[2][64*64];
    __shared__ ushort Vt[2][64*64];     // [e][s], swizzled
    __shared__ ushort Ps[4][32*64];     // per-wave P^T rows: 0-15 HI, 16-31 LO
    const int tid = threadIdx.x;
    const int w = tid >> 6, l = tid & 63;
    const int lr = l & 15, lg = l >> 4;
    const int g = blockIdx.x;
    const int bh = (g & 7) * 4 + ((g >> 3) & 3);   // 4 heads per XCD
    const int p  = g >> 5;                          // pair index 0..15
    const int qtHI = 16 + p, qtLO = 15 - p;
    const int qH0 = qtHI * 64 + w * 16;
    const int qL0 = qtLO * 64 + w * 16;

    const ushort* Q = qkvb + (size_t)bh * (TSEQ*HDIM);
    const ushort* K = Q + (size_t)2*NH*TSEQ*HDIM;
    const ushort* V = K + (size_t)2*NH*TSEQ*HDIM;

    bf16x8 qfH[2], qfL[2];
#pragma unroll
    for (int kk = 0; kk < 2; ++kk) {
        qfH[kk] = *reinterpret_cast<const bf16x8*>(&Q[(size_t)(qH0 + lr)*HDIM + kk*32 + lg*8]);
        qfL[kk] = *reinterpret_cast<const bf16x8*>(&Q[(size_t)(qL0 + lr)*HDIM + kk*32 + lg*8]);
    }

    f32x4 accH[4], accL[4];
    float mH = -3e38f, lH = 0.f, mL = -3e38f, lL = 0.f;
#pragma unroll
    for (int nf = 0; nf < 4; ++nf) { accH[nf] = {0.f,0.f,0.f,0.f}; accL[nf] = {0.f,0.f,0.f,0.f}; }

    ushort* PsW = &Ps[w][0];
    const int krow = tid >> 3, kchunk = (tid & 7) ^ ((tid >> 3) & 7);

    // ---- prologue: stage tile 0 into buf 0 ----
    {
#pragma unroll
        for (int it = 0; it < 2; ++it)
            gload16(&K[(size_t)(it*32 + krow)*HDIM + kchunk*8], &Ks[0][it*2048 + tid*8]);
        BF8 a, b;
        a.v = *reinterpret_cast<const bf16x8*>(&V[(size_t)l*HDIM + w*16]);
        b.v = *reinterpret_cast<const bf16x8*>(&V[(size_t)l*HDIM + w*16 + 8]);
#pragma unroll
        for (int j = 0; j < 8; ++j) {
            Vt[0][(w*16 + j)*64 + ((l>>3) ^ j)*8 + (l&7)] = a.u[j];
            Vt[0][(w*16 + 8 + j)*64 + ((l>>3) ^ j)*8 + (l&7)] = b.u[j];
        }
        __syncthreads();
    }

    int cur = 0;
    for (int jt = 0; jt <= qtHI; ++jt) {
        const int nxt = cur ^ 1;
        const int s0 = jt * 64;
        const bool pref = (jt < qtHI);
        const bool loAct = (jt <= qtLO);
        BF8 ga, gb;
        if (pref) {
            const int s0n = s0 + 64;
#pragma unroll
            for (int it = 0; it < 2; ++it)
                gload16(&K[(size_t)(s0n + it*32 + krow)*HDIM + kchunk*8], &Ks[nxt][it*2048 + tid*8]);
            ga.v = *reinterpret_cast<const bf16x8*>(&V[(size_t)(s0n + l)*HDIM + w*16]);
            gb.v = *reinterpret_cast<const bf16x8*>(&V[(size_t)(s0n + l)*HDIM + w*16 + 8]);
        }

        // ---- QK^T (kf shared by HI/LO) ----
        f32x4 sH[4], sL[4];
#pragma unroll
        for (int nf = 0; nf < 4; ++nf) { sH[nf] = {0.f,0.f,0.f,0.f}; sL[nf] = {0.f,0.f,0.f,0.f}; }
#pragma unroll
        for (int kk = 0; kk < 2; ++kk) {
            bf16x8 kf[4];
#pragma unroll
            for (int nf = 0; nf < 4; ++nf)
                kf[nf] = *reinterpret_cast<const bf16x8*>(
                    &Ks[cur][(nf*16 + lr)*64 + ((kk*4 + lg) ^ (lr&7))*8]);
            __builtin_amdgcn_s_setprio(1);
#pragma unroll
            for (int nf = 0; nf < 4; ++nf)
                sH[nf] = __builtin_amdgcn_mfma_f32_16x16x32_bf16(kf[nf], qfH[kk], sH[nf], 0, 0, 0);
            if (loAct) {
#pragma unroll
                for (int nf = 0; nf < 4; ++nf)
                    sL[nf] = __builtin_amdgcn_mfma_f32_16x16x32_bf16(kf[nf], qfL[kk], sL[nf], 0, 0, 0);
            }
            __builtin_amdgcn_s_setprio(0);
        }

        // ---- softmax HI ----
        {
            if (jt == qtHI) {
                int qrow = qH0 + lr;
#pragma unroll
                for (int nf = 0; nf < 4; ++nf) {
                    int kbase = s0 + nf*16 + lg*4;
#pragma unroll
                    for (int i = 0; i < 4; ++i)
                        if (kbase + i > qrow) sH[nf][i] = -1e30f;
                }
            }
            float g0 = fmax3(sH[0][0], sH[0][1], sH[0][2]);
            float g1 = fmax3(sH[0][3], sH[1][0], sH[1][1]);
            float g2 = fmax3(sH[1][2], sH[1][3], sH[2][0]);
            float g3 = fmax3(sH[2][1], sH[2][2], sH[2][3]);
            float g4 = fmax3(sH[3][0], sH[3][1], sH[3][2]);
            float tm = fmaxf(fmax3(fmax3(g0, g1, g2), g3, g4), sH[3][3]);
            tm = fmaxf(tm, __shfl_xor(tm, 16, 64));
            tm = fmaxf(tm, __shfl_xor(tm, 32, 64));
            if (__any(tm > mH + 8.0f)) {
                float mnew = fmaxf(mH, tm);
                float corr = exp2f(mH - mnew);
                lH *= corr;
#pragma unroll
                for (int nf = 0; nf < 4; ++nf)
#pragma unroll
                    for (int i = 0; i < 4; ++i) accH[nf][i] *= corr;
                mH = mnew;
            }
            float ps = 0.f;
#pragma unroll
            for (int nf = 0; nf < 4; ++nf)
#pragma unroll
                for (int i = 0; i < 4; ++i) { sH[nf][i] = exp2f(sH[nf][i] - mH); ps += sH[nf][i]; }
            ps += __shfl_xor(ps, 16, 64);
            ps += __shfl_xor(ps, 32, 64);
            lH += ps;
#pragma unroll
            for (int nf = 0; nf < 4; ++nf) {
                uint2 pk;
                pk.x = cvtpk(sH[nf][0], sH[nf][1]);
                pk.y = cvtpk(sH[nf][2], sH[nf][3]);
                *reinterpret_cast<uint2*>(
                    &PsW[lr*64 + ((2*nf + (lg>>1)) ^ (lr&7))*8 + (lg&1)*4]) = pk;
            }
        }
        // ---- softmax LO ----
        if (loAct) {
            if (jt == qtLO) {
                int qrow = qL0 + lr;
#pragma unroll
                for (int nf = 0; nf < 4; ++nf) {
                    int kbase = s0 + nf*16 + lg*4;
#pragma unroll
                    for (int i = 0; i < 4; ++i)
                        if (kbase + i > qrow) sL[nf][i] = -1e30f;
                }
            }
            float g0 = fmax3(sL[0][0], sL[0][1], sL[0][2]);
            float g1 = fmax3(sL[0][3], sL[1][0], sL[1][1]);
            float g2 = fmax3(sL[1][2], sL[1][3], sL[2][0]);
            float g3 = fmax3(sL[2][1], sL[2][2], sL[2][3]);
            float g4 = fmax3(sL[3][0], sL[3][1], sL[3][2]);
            float tm = fmaxf(fmax3(fmax3(g0, g1, g2), g3, g4), sL[3][3]);
            tm = fmaxf(tm, __shfl_xor(tm, 16, 64));
            tm = fmaxf(tm, __shfl_xor(tm, 32, 64));
            if (__any(tm > mL + 8.0f)) {
                float mnew = fmaxf(mL, tm);
                float corr = exp2f(mL - mnew);
                lL *= corr;
#pragma unroll
                for (int nf = 0; nf < 4; ++nf)
#pragma unroll
                    for (int i = 0; i < 4; ++i) accL[nf][i] *= corr;
                mL = mnew;
            }
            float ps = 0.f;
#pragma unroll
            for (int nf = 0; nf < 4; ++nf)
#pragma unroll
                for (int i = 0; i < 4; ++i) { sL[nf][i] = exp2f(sL[nf][i] - mL); ps += sL[nf][i]; }
            ps += __shfl_xor(ps, 16, 64);
            ps += __shfl_xor(ps, 32, 64);
            lL += ps;
#pragma unroll
            for (int nf = 0; nf < 4; ++nf) {
                uint2 pk;
                pk.x = cvtpk(sL[nf][0], sL[nf][1]);
                pk.y = cvtpk(sL[nf][2], sL[nf][3]);
                *reinterpret_cast<uint2*>(
                    &PsW[(16 + lr)*64 + ((2*nf + (lg>>1)) ^ (lr&7))*8 + (lg&1)*4]) = pk;
            }
        }

        // ---- PV (vf shared by HI/LO) ----
#pragma unroll
        for (int kk = 0; kk < 2; ++kk) {
            bf16x8 vf[4];
#pragma unroll
            for (int nf = 0; nf < 4; ++nf)
                vf[nf] = *reinterpret_cast<const bf16x8*>(
                    &Vt[cur][(nf*16 + lr)*64 + ((kk*4 + lg) ^ (lr&7))*8]);
            bf16x8 pfH = *reinterpret_cast<const bf16x8*>(
                &PsW[lr*64 + ((kk*4 + lg) ^ (lr&7))*8]);
            __builtin_amdgcn_s_setprio(1);
#pragma unroll
            for (int nf = 0; nf < 4; ++nf)
                accH[nf] = __builtin_amdgcn_mfma_f32_16x16x32_bf16(vf[nf], pfH, accH[nf], 0, 0, 0);
            __builtin_amdgcn_s_setprio(0);
            if (loAct) {
                bf16x8 pfL = *reinterpret_cast<const bf16x8*>(
                    &PsW[(16 + lr)*64 + ((kk*4 + lg) ^ (lr&7))*8]);
                __builtin_amdgcn_s_setprio(1);
#pragma unroll
                for (int nf = 0; nf < 4; ++nf)
                    accL[nf] = __builtin_amdgcn_mfma_f32_16x16x32_bf16(vf[nf], pfL, accL[nf], 0, 0, 0);
                __builtin_amdgcn_s_setprio(0);
            }
        }

        // ---- finish staging next tile's V (loads issued at top) ----
        if (pref) {
#pragma unroll
            for (int j = 0; j < 8; ++j) {
                Vt[nxt][(w*16 + j)*64 + ((l>>3) ^ j)*8 + (l&7)] = ga.u[j];
                Vt[nxt][(w*16 + 8 + j)*64 + ((l>>3) ^ j)*8 + (l&7)] = gb.u[j];
            }
        }
        __syncthreads();
        cur = nxt;
    }

    // ---- epilogue: lane holds O^T[e = nf*16+lg*4+i][q = q?0+lr] ----
    const int b = bh >> 4, h = bh & 15;
    {
        float inv = 1.0f / lH;
        int t = qH0 + lr;
        ushort* o = concatb + ((size_t)(b*TSEQ + t))*DM + h*HDIM;
#pragma unroll
        for (int nf = 0; nf < 4; ++nf) {
            uint2 pk;
            pk.x = cvtpk(accH[nf][0]*inv, accH[nf][1]*inv);
            pk.y = cvtpk(accH[nf][2]*inv, accH[nf][3]*inv);
            *reinterpret_cast<uint2*>(&o[nf*16 + lg*4]) = pk;
        }
    }
    {
        float inv = 1.0f / lL;
        int t = qL0 + lr;
        ushort* o = concatb + ((size_t)(b*TSEQ + t))*DM + h*HDIM;
#pragma unroll
        for (int nf = 0; nf < 4; ++nf) {
            uint2 pk;
            pk.x = cvtpk(accL[nf][0]*inv, accL[nf][1]*inv);
            pk.y = cvtpk(accL[nf][2]*inv, accL[nf][3]*inv);
            *reinterpret_cast<uint2*>(&o[nf*16 + lg*4]) = pk;
        }
    }
}

// ---------------------------------------------------------------------------
extern "C" void kernel_launch(void* const* d_in, const int* in_sizes, int n_in,
                              void* d_out, int out_size, void* d_ws, size_t ws_size,
                              hipStream_t stream) {
    const float* x  = (const float*)d_in[0];
    const float* Wq = (const float*)d_in[1];
    const float* Wk = (const float*)d_in[2];
    const float* Wv = (const float*)d_in[3];
    const float* Wp = (const float*)d_in[4];
    const float* bp = (const float*)d_in[5];
    float* out = (float*)d_out;

    ushort* ws   = (ushort*)d_ws;
    ushort* xb   = ws;                                    // BT*DM
    ushort* wtb  = xb  + (size_t)BT*DM;                   // [3072][1024]
    ushort* wpb  = wtb + (size_t)3*NH*HDIM*DM;            // DM*DM
    ushort* qkvb = wpb + (size_t)DM*DM;                   // [3][B*H][T][HD]
    ushort* cb   = qkvb + (size_t)3*2*NH*TSEQ*HDIM;       // BT*DM

    cvt_kernel<<<dim3((BT*DM/8 + 255)/256), 256, 0, stream>>>(x, xb, BT*DM/8);
    wt_kernel<<<dim3(DM/64, 3*NH), 256, 0, stream>>>(Wq, Wk, Wv, wtb);
    cvt_kernel<<<dim3(DM*DM/8/256), 256, 0, stream>>>(Wp, wpb, DM*DM/8);
    gemm_bt<0><<<dim3(32*24), 256, 0, stream>>>(xb, wtb, nullptr, qkvb);
    attn_mfma<<<dim3(512), 256, 0, stream>>>(qkvb, cb);
    gemm_bt<1><<<dim3(32*8), 256, 0, stream>>>(cb, wpb, bp, out);
}